// Round 13
// baseline (292.504 us; speedup 1.0000x reference)
//
#include <hip/hip_runtime.h>
#include <hip/hip_fp16.h>
#include <math.h>

#define NROWS 8192
#define DDIM 384
#define HDIM 256
#define CDIM 6
#define LN_EPS 1e-5f
#define DSTR 138   // Dt row stride in halves (69 dwords, odd)

typedef short bf16x8 __attribute__((ext_vector_type(8)));
typedef float f32x4 __attribute__((ext_vector_type(4)));
typedef unsigned short u16x8 __attribute__((ext_vector_type(8)));
typedef unsigned short u16x4 __attribute__((ext_vector_type(4)));
typedef unsigned short u16x2 __attribute__((ext_vector_type(2)));

__device__ __forceinline__ bool dj_better(float d1, int j1, float d2, int j2) {
    return (d1 < d2) || (d1 == d2 && j1 < j2);
}

__device__ __forceinline__ unsigned int umin_(unsigned int a, unsigned int b) { return a < b ? a : b; }
__device__ __forceinline__ unsigned int umax_(unsigned int a, unsigned int b) { return a > b ? a : b; }

// fp32 -> fp16 -> monotonic u16 (unsigned order == float order)
__device__ __forceinline__ unsigned short map16f(float v) {
    union { _Float16 f; unsigned short u; } c;
    c.f = (_Float16)v;
    unsigned short b = c.u;
    return (unsigned short)(b ^ (unsigned short)((((short)b) >> 15) | 0x8000));
}

__device__ __forceinline__ unsigned short rne_bf16(float v) {
    unsigned int u = __float_as_uint(v);
    u += 0x7fffu + ((u >> 16) & 1u);
    return (unsigned short)(u >> 16);
}

// branchless unsorted 8-slot top-8 insert (replace current max, recompute max)
__device__ __forceinline__ void ins8(
    unsigned int& s0, unsigned int& s1, unsigned int& s2, unsigned int& s3,
    unsigned int& s4, unsigned int& s5, unsigned int& s6, unsigned int& s7,
    unsigned int& m, unsigned int key)
{
    if (key < m) {
        s0 = (s0 == m) ? key : s0;
        s1 = (s1 == m) ? key : s1;
        s2 = (s2 == m) ? key : s2;
        s3 = (s3 == m) ? key : s3;
        s4 = (s4 == m) ? key : s4;
        s5 = (s5 == m) ? key : s5;
        s6 = (s6 == m) ? key : s6;
        s7 = (s7 == m) ? key : s7;
        m = umax_(umax_(umax_(s0, s1), umax_(s2, s3)),
                  umax_(umax_(s4, s5), umax_(s6, s7)));
    }
}

// ---------------- prep: xb = bf16(x), sq[i] = ||x_i||^2, k[i] from tau ----------------
__global__ void __launch_bounds__(256) precompute_kernel(
    const float* __restrict__ x, const float* __restrict__ W_tau,
    const float* __restrict__ b_tau, unsigned short* __restrict__ xb,
    float* __restrict__ sq, int* __restrict__ kk)
{
    int tid = threadIdx.x;
    int wave = tid >> 6, lane = tid & 63;
    int row = blockIdx.x * 4 + wave;
    const float* xr = x + (size_t)row * DDIM;
    unsigned short* xbr = xb + (size_t)row * DDIM;
    float s = 0.f, tp = 0.f;
    #pragma unroll
    for (int q = 0; q < 6; ++q) {
        float v = xr[lane + 64 * q];
        xbr[lane + 64 * q] = rne_bf16(v);
        s = fmaf(v, v, s);
        tp = fmaf(v, W_tau[lane + 64 * q], tp);
    }
    #pragma unroll
    for (int off = 32; off > 0; off >>= 1) {
        s += __shfl_xor(s, off);
        tp += __shfl_xor(tp, off);
    }
    if (lane == 0) {
        sq[row] = s;
        float u = tp + b_tau[0];
        float tau = 1.f / (1.f + expf(-u));
        float kf = rintf(16.f - 12.f * tau);
        int k = (int)kf;
        k = min(16, max(1, k));
        kk[row] = k;
    }
}

// ---------------- both weight transposes (fp32 [K][N] -> bf16 [N][K]) ----------------
__global__ void __launch_bounds__(256) transpose_bf16_kernel(
    const float* __restrict__ Wp, unsigned short* __restrict__ wpT,
    const float* __restrict__ Wr, unsigned short* __restrict__ wrT)
{
    int i = blockIdx.x * 256 + threadIdx.x;
    if (i < DDIM * HDIM) {
        int k = i / HDIM, n = i % HDIM;
        wpT[(size_t)n * DDIM + k] = rne_bf16(Wp[i]);
    } else {
        int j = i - DDIM * HDIM;
        if (j < HDIM * HDIM) {
            int k = j / HDIM, n = j % HDIM;
            wrT[(size_t)n * HDIM + k] = rne_bf16(Wr[j]);
        }
    }
}

// ---------------- MFMA bf16 GEMM: out = relu(A[M,K]@W + bias), W given as WT[n][k] ----------------
__global__ void __launch_bounds__(256) mfma_gemm_bias_relu_kernel(
    const unsigned short* __restrict__ A, const unsigned short* __restrict__ WT,
    const float* __restrict__ bias, float* __restrict__ out, int K)
{
    __shared__ unsigned short Abuf[128 * 32];
    __shared__ unsigned short Bbuf[128 * 32];

    const int tid = threadIdx.x;
    const int wave = tid >> 6;
    const int rowbase = blockIdx.x * 128;
    const int nbase = blockIdx.y * 128;
    const int lane = tid & 63;
    const int wr = (wave >> 1) * 64;
    const int wc = (wave & 1) * 64;
    const int m16 = lane & 15;
    const int kq = lane >> 4;

    const int er0 = tid >> 2;
    const int er1 = 64 + (tid >> 2);
    const int eko = tid & 3;

    f32x4 acc[4][4];
    #pragma unroll
    for (int a = 0; a < 4; ++a)
        #pragma unroll
        for (int b = 0; b < 4; ++b)
            acc[a][b] = (f32x4){0.f, 0.f, 0.f, 0.f};

    for (int kb = 0; kb < K / 32; ++kb) {
        const int k0 = kb * 32;
        __syncthreads();
        __builtin_amdgcn_global_load_lds(
            (const __attribute__((address_space(1))) void*)(A + (size_t)(rowbase + er0) * K + k0 + eko * 8),
            (__attribute__((address_space(3))) void*)((char*)Abuf + (wave * 64) * 16), 16, 0, 0);
        __builtin_amdgcn_global_load_lds(
            (const __attribute__((address_space(1))) void*)(A + (size_t)(rowbase + er1) * K + k0 + eko * 8),
            (__attribute__((address_space(3))) void*)((char*)Abuf + (256 + wave * 64) * 16), 16, 0, 0);
        __builtin_amdgcn_global_load_lds(
            (const __attribute__((address_space(1))) void*)(WT + (size_t)(nbase + er0) * K + k0 + eko * 8),
            (__attribute__((address_space(3))) void*)((char*)Bbuf + (wave * 64) * 16), 16, 0, 0);
        __builtin_amdgcn_global_load_lds(
            (const __attribute__((address_space(1))) void*)(WT + (size_t)(nbase + er1) * K + k0 + eko * 8),
            (__attribute__((address_space(3))) void*)((char*)Bbuf + (256 + wave * 64) * 16), 16, 0, 0);
        __syncthreads();

        bf16x8 af[4], bfr[4];
        #pragma unroll
        for (int s = 0; s < 4; ++s) {
            af[s]  = *(const bf16x8*)&Abuf[(wr + s * 16 + m16) * 32 + kq * 8];
            bfr[s] = *(const bf16x8*)&Bbuf[(wc + s * 16 + m16) * 32 + kq * 8];
        }
        #pragma unroll
        for (int si = 0; si < 4; ++si)
            #pragma unroll
            for (int sj = 0; sj < 4; ++sj)
                acc[si][sj] = __builtin_amdgcn_mfma_f32_16x16x32_bf16(
                    af[si], bfr[sj], acc[si][sj], 0, 0, 0);
    }

    #pragma unroll
    for (int sj = 0; sj < 4; ++sj) {
        int c = nbase + wc + sj * 16 + m16;
        float bc = bias[c];
        #pragma unroll
        for (int si = 0; si < 4; ++si) {
            int r = rowbase + wr + si * 16 + kq * 4;
            #pragma unroll
            for (int v = 0; v < 4; ++v)
                out[(size_t)(r + v) * HDIM + c] = fmaxf(acc[si][sj][v] + bc, 0.f);
        }
    }
}

// ---------------- MFMA bf16 Gram GEMM + fused per-tile top-8 screening ----------------
// R12 structure, plus overlay double-buffered staging: the second A/B staging
// buffers live inside Dt (dead during K-loop) -> one barrier per k-step,
// prefetch overlaps MFMA, zero LDS growth.
__global__ void __launch_bounds__(256) dist_topk_kernel(
    const unsigned short* __restrict__ xb, const float* __restrict__ sq,
    unsigned int* __restrict__ keys)
{
    __shared__ unsigned short Abuf[128 * 32];                 // 8 KB (buf0 A)
    __shared__ unsigned short Bbuf[128 * 32];                 // 8 KB (buf0 B)
    __shared__ __align__(16) unsigned short Dt[128 * DSTR];   // 34.5 KB; first 16 KB doubles as buf1

    unsigned short* A1 = Dt;                // 8 KB
    unsigned short* B1 = Dt + 128 * 32;     // 8 KB

    int t = blockIdx.x;
    int bi = (int)((sqrtf(8.f * (float)t + 1.f) - 1.f) * 0.5f);
    while ((bi + 1) * (bi + 2) / 2 <= t) ++bi;
    while (bi * (bi + 1) / 2 > t) --bi;
    int bj = t - bi * (bi + 1) / 2;

    const int tid = threadIdx.x;
    const int wave = tid >> 6;
    const int lane = tid & 63;
    const int rowbase = bi * 128;
    const int colbase = bj * 128;
    const int wr = (wave >> 1) * 64;
    const int wc = (wave & 1) * 64;
    const int m16 = lane & 15;
    const int kq = lane >> 4;

    const int er0 = tid >> 2;
    const int er1 = 64 + (tid >> 2);
    const int eko = tid & 3;

#define ISSUE_LOADS(K0, AB, BB)                                                                     \
    do {                                                                                            \
        __builtin_amdgcn_global_load_lds(                                                           \
            (const __attribute__((address_space(1))) void*)(xb + (size_t)(rowbase + er0) * DDIM + (K0) + eko * 8), \
            (__attribute__((address_space(3))) void*)((char*)(AB) + (wave * 64) * 16), 16, 0, 0);   \
        __builtin_amdgcn_global_load_lds(                                                           \
            (const __attribute__((address_space(1))) void*)(xb + (size_t)(rowbase + er1) * DDIM + (K0) + eko * 8), \
            (__attribute__((address_space(3))) void*)((char*)(AB) + (256 + wave * 64) * 16), 16, 0, 0); \
        __builtin_amdgcn_global_load_lds(                                                           \
            (const __attribute__((address_space(1))) void*)(xb + (size_t)(colbase + er0) * DDIM + (K0) + eko * 8), \
            (__attribute__((address_space(3))) void*)((char*)(BB) + (wave * 64) * 16), 16, 0, 0);   \
        __builtin_amdgcn_global_load_lds(                                                           \
            (const __attribute__((address_space(1))) void*)(xb + (size_t)(colbase + er1) * DDIM + (K0) + eko * 8), \
            (__attribute__((address_space(3))) void*)((char*)(BB) + (256 + wave * 64) * 16), 16, 0, 0); \
    } while (0)

#define COMPUTE_STEP(AB, BB)                                                                        \
    do {                                                                                            \
        bf16x8 af[4], bfr[4];                                                                       \
        _Pragma("unroll")                                                                           \
        for (int s = 0; s < 4; ++s) {                                                               \
            af[s]  = *(const bf16x8*)&(AB)[(wr + s * 16 + m16) * 32 + kq * 8];                      \
            bfr[s] = *(const bf16x8*)&(BB)[(wc + s * 16 + m16) * 32 + kq * 8];                      \
        }                                                                                           \
        _Pragma("unroll")                                                                           \
        for (int si = 0; si < 4; ++si)                                                              \
            _Pragma("unroll")                                                                       \
            for (int sj = 0; sj < 4; ++sj)                                                          \
                acc[si][sj] = __builtin_amdgcn_mfma_f32_16x16x32_bf16(                              \
                    af[si], bfr[sj], acc[si][sj], 0, 0, 0);                                         \
    } while (0)

    f32x4 acc[4][4];
    #pragma unroll
    for (int a = 0; a < 4; ++a)
        #pragma unroll
        for (int b = 0; b < 4; ++b)
            acc[a][b] = (f32x4){0.f, 0.f, 0.f, 0.f};

    ISSUE_LOADS(0, Abuf, Bbuf);
    for (int kb = 0; kb < DDIM / 32; kb += 2) {
        __syncthreads();                                  // drains buf0 loads (step kb)
        if (kb + 1 < DDIM / 32) ISSUE_LOADS((kb + 1) * 32, A1, B1);
        COMPUTE_STEP(Abuf, Bbuf);
        __syncthreads();                                  // drains buf1 loads (step kb+1)
        if (kb + 2 < DDIM / 32) ISSUE_LOADS((kb + 2) * 32, Abuf, Bbuf);
        COMPUTE_STEP(A1, B1);
    }
    __syncthreads();   // all ds_reads of Dt-hosted buf1 done before epilogue overwrites Dt

    const int sr = tid >> 1;          // scan row in tile (0..127)
    const int seg = tid & 1;          // 64-col half

    // ==== pass 1: rows of bi-block ====
    {
        float sqc[4];
        #pragma unroll
        for (int sj = 0; sj < 4; ++sj) sqc[sj] = sq[colbase + wc + sj * 16 + m16];
        #pragma unroll
        for (int si = 0; si < 4; ++si)
            #pragma unroll
            for (int sj = 0; sj < 4; ++sj) {
                int r = wr + si * 16 + kq * 4;
                int c = wc + sj * 16 + m16;
                #pragma unroll
                for (int v = 0; v < 4; ++v)
                    Dt[(r + v) * DSTR + c] = map16f(sqc[sj] - 2.0f * acc[si][sj][v]);
            }
        __syncthreads();

        unsigned int s0 = 0xFFFFFFFFu, s1 = 0xFFFFFFFEu, s2 = 0xFFFFFFFDu, s3 = 0xFFFFFFFCu;
        unsigned int s4 = 0xFFFFFFFBu, s5 = 0xFFFFFFFAu, s6 = 0xFFFFFFF9u, s7 = 0xFFFFFFF8u;
        unsigned int m = 0xFFFFFFFFu;
        const unsigned short* rowp = &Dt[sr * DSTR + seg * 64];
        #pragma unroll
        for (int i = 0; i < 8; ++i) {
            u16x8 ch = *(const u16x8*)(rowp + i * 8);
            u16x4 g4 = __builtin_elementwise_min(
                __builtin_shufflevector(ch, ch, 0, 1, 2, 3),
                __builtin_shufflevector(ch, ch, 4, 5, 6, 7));
            u16x2 g2 = __builtin_elementwise_min(
                __builtin_shufflevector(g4, g4, 0, 1),
                __builtin_shufflevector(g4, g4, 2, 3));
            unsigned int gmin = umin_((unsigned int)g2[0], (unsigned int)g2[1]);
            if ((gmin << 13) < m) {
                int cb = colbase + seg * 64 + i * 8;
                #pragma unroll
                for (int e = 0; e < 8; ++e)
                    ins8(s0, s1, s2, s3, s4, s5, s6, s7, m,
                         ((unsigned int)ch[e] << 13) | (unsigned int)(cb + e));
            }
        }
        size_t kb = (size_t)(rowbase + sr) * 1024 + (size_t)bj * 16 + seg * 8;
        uint4 o0; o0.x = s0; o0.y = s1; o0.z = s2; o0.w = s3;
        uint4 o1; o1.x = s4; o1.y = s5; o1.z = s6; o1.w = s7;
        *(uint4*)&keys[kb] = o0;
        *(uint4*)&keys[kb + 4] = o1;
    }

    // ==== pass 2: rows of bj-block via transposed tile (off-diagonal only) ====
    if (bi != bj) {
        __syncthreads();
        #pragma unroll
        for (int si = 0; si < 4; ++si) {
            float4 sqr4 = *(const float4*)&sq[rowbase + wr + si * 16 + kq * 4];
            float srw[4] = {sqr4.x, sqr4.y, sqr4.z, sqr4.w};
            #pragma unroll
            for (int sj = 0; sj < 4; ++sj) {
                int r = wr + si * 16 + kq * 4;
                int c = wc + sj * 16 + m16;
                unsigned short h4[4];
                #pragma unroll
                for (int v = 0; v < 4; ++v)
                    h4[v] = map16f(srw[v] - 2.0f * acc[si][sj][v]);
                *(unsigned long long*)&Dt[c * DSTR + r] = *(unsigned long long*)h4;
            }
        }
        __syncthreads();

        unsigned int s0 = 0xFFFFFFFFu, s1 = 0xFFFFFFFEu, s2 = 0xFFFFFFFDu, s3 = 0xFFFFFFFCu;
        unsigned int s4 = 0xFFFFFFFBu, s5 = 0xFFFFFFFAu, s6 = 0xFFFFFFF9u, s7 = 0xFFFFFFF8u;
        unsigned int m = 0xFFFFFFFFu;
        const unsigned short* rowp = &Dt[sr * DSTR + seg * 64];
        #pragma unroll
        for (int i = 0; i < 8; ++i) {
            u16x8 ch = *(const u16x8*)(rowp + i * 8);
            u16x4 g4 = __builtin_elementwise_min(
                __builtin_shufflevector(ch, ch, 0, 1, 2, 3),
                __builtin_shufflevector(ch, ch, 4, 5, 6, 7));
            u16x2 g2 = __builtin_elementwise_min(
                __builtin_shufflevector(g4, g4, 0, 1),
                __builtin_shufflevector(g4, g4, 2, 3));
            unsigned int gmin = umin_((unsigned int)g2[0], (unsigned int)g2[1]);
            if ((gmin << 13) < m) {
                int cb = rowbase + seg * 64 + i * 8;
                #pragma unroll
                for (int e = 0; e < 8; ++e)
                    ins8(s0, s1, s2, s3, s4, s5, s6, s7, m,
                         ((unsigned int)ch[e] << 13) | (unsigned int)(cb + e));
            }
        }
        size_t kb = (size_t)(colbase + sr) * 1024 + (size_t)bi * 16 + seg * 8;
        uint4 o0; o0.x = s0; o0.y = s1; o0.z = s2; o0.w = s3;
        uint4 o1; o1.x = s4; o1.y = s5; o1.z = s6; o1.w = s7;
        *(uint4*)&keys[kb] = o0;
        *(uint4*)&keys[kb + 4] = o1;
    }
#undef ISSUE_LOADS
#undef COMPUTE_STEP
}

// ---------------- merge per-tile keys -> top-32 candidates (1 wave / row) ----------------
__global__ void __launch_bounds__(256) select_merge_kernel(
    const unsigned int* __restrict__ keys, int* __restrict__ cand)
{
    const int row = blockIdx.x * 4 + (threadIdx.x >> 6);
    const int lane = threadIdx.x & 63;
    const uint4* kp = (const uint4*)(keys + (size_t)row * 1024 + lane * 16);

    unsigned int s0 = 0xFFFFFFFFu, s1 = 0xFFFFFFFEu, s2 = 0xFFFFFFFDu, s3 = 0xFFFFFFFCu;
    unsigned int s4 = 0xFFFFFFFBu, s5 = 0xFFFFFFFAu, s6 = 0xFFFFFFF9u, s7 = 0xFFFFFFF8u;
    unsigned int m = 0xFFFFFFFFu;

    #pragma unroll
    for (int q = 0; q < 4; ++q) {
        uint4 v = kp[q];
        unsigned int gmin = umin_(umin_(v.x, v.y), umin_(v.z, v.w));
        if (gmin < m) {
            ins8(s0, s1, s2, s3, s4, s5, s6, s7, m, v.x);
            ins8(s0, s1, s2, s3, s4, s5, s6, s7, m, v.y);
            ins8(s0, s1, s2, s3, s4, s5, s6, s7, m, v.z);
            ins8(s0, s1, s2, s3, s4, s5, s6, s7, m, v.w);
        }
    }

    unsigned int lmin = umin_(umin_(umin_(s0, s1), umin_(s2, s3)),
                              umin_(umin_(s4, s5), umin_(s6, s7)));
    unsigned int myout = 0;
    for (int t = 0; t < 32; ++t) {
        unsigned int w = lmin;
        #pragma unroll
        for (int off = 32; off > 0; off >>= 1)
            w = umin_(w, (unsigned int)__shfl_xor((int)w, off));
        if (lane == t) myout = w;
        if (lmin == w) {
            s0 = (s0 == w) ? 0xFFFFFFFFu : s0;
            s1 = (s1 == w) ? 0xFFFFFFFFu : s1;
            s2 = (s2 == w) ? 0xFFFFFFFFu : s2;
            s3 = (s3 == w) ? 0xFFFFFFFFu : s3;
            s4 = (s4 == w) ? 0xFFFFFFFFu : s4;
            s5 = (s5 == w) ? 0xFFFFFFFFu : s5;
            s6 = (s6 == w) ? 0xFFFFFFFFu : s6;
            s7 = (s7 == w) ? 0xFFFFFFFFu : s7;
            lmin = umin_(umin_(umin_(s0, s1), umin_(s2, s3)),
                         umin_(umin_(s4, s5), umin_(s6, s7)));
        }
    }
    if (lane < 32)
        cand[(size_t)row * 32 + lane] = (int)(myout & 8191u);
}

// ---------------- exact fp32 rescore -> top-16, fused with gather-mean agg ----------------
__global__ void __launch_bounds__(256) rescore_agg_kernel(
    const float* __restrict__ x, const float* __restrict__ sq,
    const int* __restrict__ cand, const int* __restrict__ kk,
    const float* __restrict__ h, unsigned short* __restrict__ aggb)
{
    const int w = threadIdx.x >> 6;
    const int row = blockIdx.x * 4 + w;
    const int lane = threadIdx.x & 63;
    __shared__ int sidx[4][16];

    float xr[6];
    #pragma unroll
    for (int q = 0; q < 6; ++q) xr[q] = x[(size_t)row * DDIM + lane + 64 * q];
    int myj = cand[(size_t)row * 32 + (lane & 31)];
    float sqrow = sq[row];
    float myd = 0.f;
    for (int c = 0; c < 32; ++c) {
        int j = __shfl(myj, c);
        const float* xc = x + (size_t)j * DDIM;
        float p = 0.f;
        #pragma unroll
        for (int q = 0; q < 6; ++q) p = fmaf(xr[q], xc[lane + 64 * q], p);
        #pragma unroll
        for (int off = 32; off > 0; off >>= 1) p += __shfl_xor(p, off);
        float d = sqrow + sq[j] - 2.f * p;
        if (lane == c) myd = d;
    }
    int rank = 0;
    for (int t = 0; t < 32; ++t) {
        float dt = __shfl(myd, t); int jt = __shfl(myj, t);
        if (dj_better(dt, jt, myd, myj)) ++rank;
    }
    if (lane < 32 && rank < 16) sidx[w][rank] = myj;
    __syncthreads();

    // gather-mean of first k neighbors' h rows (4 fp32 chunks per lane)
    int k = kk[row];
    float a0 = 0.f, a1 = 0.f, a2 = 0.f, a3 = 0.f;
    for (int t = 0; t < k; ++t) {
        const float* hr = h + (size_t)sidx[w][t] * HDIM;
        a0 += hr[lane];
        a1 += hr[lane + 64];
        a2 += hr[lane + 128];
        a3 += hr[lane + 192];
    }
    float inv = 1.f / (float)k;
    unsigned short* ar = aggb + (size_t)row * HDIM;
    ar[lane]       = rne_bf16(a0 * inv);
    ar[lane + 64]  = rne_bf16(a1 * inv);
    ar[lane + 128] = rne_bf16(a2 * inv);
    ar[lane + 192] = rne_bf16(a3 * inv);
}

// ---------------- LayerNorm(h + r) * g + b, then @ W_fc + b_fc ----------------
__global__ void __launch_bounds__(256) ln_fc_kernel(
    const float* __restrict__ h, const float* __restrict__ r,
    const float* __restrict__ g, const float* __restrict__ bb,
    const float* __restrict__ W_fc, const float* __restrict__ b_fc,
    float* __restrict__ out)
{
    int row = blockIdx.x, tid = threadIdx.x;
    int wave = tid >> 6, lane = tid & 63;
    float z = h[(size_t)row * HDIM + tid] + r[(size_t)row * HDIM + tid];
    float s = z, s2 = z * z;
    #pragma unroll
    for (int off = 32; off > 0; off >>= 1) { s += __shfl_xor(s, off); s2 += __shfl_xor(s2, off); }
    __shared__ float red[8];
    __shared__ float smv[2];
    if (lane == 0) { red[wave] = s; red[4 + wave] = s2; }
    __syncthreads();
    if (tid == 0) {
        float ts = red[0] + red[1] + red[2] + red[3];
        float t2 = red[4] + red[5] + red[6] + red[7];
        float mu = ts / 256.f;
        float var = t2 / 256.f - mu * mu;
        smv[0] = mu; smv[1] = rsqrtf(var + LN_EPS);
    }
    __syncthreads();
    float zn = (z - smv[0]) * smv[1];
    float val = zn * g[tid] + bb[tid];
    float p[6];
    #pragma unroll
    for (int c = 0; c < 6; ++c) p[c] = val * W_fc[tid * 6 + c];
    #pragma unroll
    for (int c = 0; c < 6; ++c)
        #pragma unroll
        for (int off = 32; off > 0; off >>= 1) p[c] += __shfl_xor(p[c], off);
    __shared__ float pr[4][6];
    if (lane == 0) {
        #pragma unroll
        for (int c = 0; c < 6; ++c) pr[wave][c] = p[c];
    }
    __syncthreads();
    if (tid < 6)
        out[(size_t)row * CDIM + tid] = pr[0][tid] + pr[1][tid] + pr[2][tid] + pr[3][tid] + b_fc[tid];
}

extern "C" void kernel_launch(void* const* d_in, const int* in_sizes, int n_in,
                              void* d_out, int out_size, void* d_ws, size_t ws_size,
                              hipStream_t stream) {
    const float* x      = (const float*)d_in[0];
    const float* W_proj = (const float*)d_in[1];
    const float* b_proj = (const float*)d_in[2];
    const float* W_tau  = (const float*)d_in[3];
    const float* b_tau  = (const float*)d_in[4];
    const float* W_res  = (const float*)d_in[5];
    const float* b_res  = (const float*)d_in[6];
    const float* ln_g   = (const float*)d_in[7];
    const float* ln_b   = (const float*)d_in[8];
    const float* W_fc   = (const float*)d_in[9];
    const float* b_fc   = (const float*)d_in[10];
    float* out = (float*)d_out;

    char* ws = (char*)d_ws;
    float* sq   = (float*)ws;                        ws += (size_t)NROWS * 4;
    int*   kk   = (int*)ws;                          ws += (size_t)NROWS * 4;
    float* h    = (float*)ws;                        ws += (size_t)NROWS * HDIM * 4;
    float* r    = (float*)ws;                        ws += (size_t)NROWS * HDIM * 4;
    int*   cand = (int*)ws;                          ws += (size_t)NROWS * 32 * 4;
    unsigned short* xb   = (unsigned short*)ws;      ws += (size_t)NROWS * DDIM * 2;
    unsigned short* aggb = (unsigned short*)ws;      ws += (size_t)NROWS * HDIM * 2;
    unsigned short* wpT  = (unsigned short*)ws;      ws += (size_t)DDIM * HDIM * 2;
    unsigned short* wrT  = (unsigned short*)ws;      ws += (size_t)HDIM * HDIM * 2;
    ws = (char*)(((size_t)ws + 255) & ~(size_t)255);
    unsigned int* keys = (unsigned int*)ws;          ws += (size_t)NROWS * 1024 * 4;   // 32 MB

    precompute_kernel<<<NROWS / 4, 256, 0, stream>>>(x, W_tau, b_tau, xb, sq, kk);
    transpose_bf16_kernel<<<(DDIM * HDIM + HDIM * HDIM + 255) / 256, 256, 0, stream>>>(
        W_proj, wpT, W_res, wrT);
    mfma_gemm_bias_relu_kernel<<<dim3(NROWS / 128, HDIM / 128), 256, 0, stream>>>(
        xb, wpT, b_proj, h, DDIM);
    dist_topk_kernel<<<(NROWS/128) * (NROWS/128 + 1) / 2, 256, 0, stream>>>(xb, sq, keys);
    select_merge_kernel<<<NROWS / 4, 256, 0, stream>>>(keys, cand);
    rescore_agg_kernel<<<NROWS / 4, 256, 0, stream>>>(x, sq, cand, kk, h, aggb);
    mfma_gemm_bias_relu_kernel<<<dim3(NROWS / 128, HDIM / 128), 256, 0, stream>>>(
        aggb, wrT, b_res, r, HDIM);
    ln_fc_kernel<<<NROWS, 256, 0, stream>>>(h, r, ln_g, ln_b, W_fc, b_fc, out);
}

// Round 14
// 277.101 us; speedup vs baseline: 1.0556x; 1.0556x over previous
//
#include <hip/hip_runtime.h>
#include <hip/hip_fp16.h>
#include <math.h>

#define NROWS 8192
#define DDIM 384
#define HDIM 256
#define CDIM 6
#define LN_EPS 1e-5f
#define DSTR 138   // Dt row stride in halves (69 dwords, odd -> conflict-free scan)

typedef short bf16x8 __attribute__((ext_vector_type(8)));
typedef float f32x4 __attribute__((ext_vector_type(4)));
typedef unsigned short u16x8 __attribute__((ext_vector_type(8)));
typedef unsigned short u16x4 __attribute__((ext_vector_type(4)));
typedef unsigned short u16x2 __attribute__((ext_vector_type(2)));

__device__ __forceinline__ bool dj_better(float d1, int j1, float d2, int j2) {
    return (d1 < d2) || (d1 == d2 && j1 < j2);
}

__device__ __forceinline__ unsigned int umin_(unsigned int a, unsigned int b) { return a < b ? a : b; }
__device__ __forceinline__ unsigned int umax_(unsigned int a, unsigned int b) { return a > b ? a : b; }

// fp32 -> fp16 -> monotonic u16 (unsigned order == float order)
__device__ __forceinline__ unsigned short map16f(float v) {
    union { _Float16 f; unsigned short u; } c;
    c.f = (_Float16)v;
    unsigned short b = c.u;
    return (unsigned short)(b ^ (unsigned short)((((short)b) >> 15) | 0x8000));
}

__device__ __forceinline__ unsigned short rne_bf16(float v) {
    unsigned int u = __float_as_uint(v);
    u += 0x7fffu + ((u >> 16) & 1u);
    return (unsigned short)(u >> 16);
}

// branchless unsorted 8-slot top-8 insert (replace current max, recompute max)
__device__ __forceinline__ void ins8(
    unsigned int& s0, unsigned int& s1, unsigned int& s2, unsigned int& s3,
    unsigned int& s4, unsigned int& s5, unsigned int& s6, unsigned int& s7,
    unsigned int& m, unsigned int key)
{
    if (key < m) {
        s0 = (s0 == m) ? key : s0;
        s1 = (s1 == m) ? key : s1;
        s2 = (s2 == m) ? key : s2;
        s3 = (s3 == m) ? key : s3;
        s4 = (s4 == m) ? key : s4;
        s5 = (s5 == m) ? key : s5;
        s6 = (s6 == m) ? key : s6;
        s7 = (s7 == m) ? key : s7;
        m = umax_(umax_(umax_(s0, s1), umax_(s2, s3)),
                  umax_(umax_(s4, s5), umax_(s6, s7)));
    }
}

// ---------------- prep: xb = bf16(x), sq[i] = ||x_i||^2, k[i] from tau ----------------
__global__ void __launch_bounds__(256) precompute_kernel(
    const float* __restrict__ x, const float* __restrict__ W_tau,
    const float* __restrict__ b_tau, unsigned short* __restrict__ xb,
    float* __restrict__ sq, int* __restrict__ kk)
{
    int tid = threadIdx.x;
    int wave = tid >> 6, lane = tid & 63;
    int row = blockIdx.x * 4 + wave;
    const float* xr = x + (size_t)row * DDIM;
    unsigned short* xbr = xb + (size_t)row * DDIM;
    float s = 0.f, tp = 0.f;
    #pragma unroll
    for (int q = 0; q < 6; ++q) {
        float v = xr[lane + 64 * q];
        xbr[lane + 64 * q] = rne_bf16(v);
        s = fmaf(v, v, s);
        tp = fmaf(v, W_tau[lane + 64 * q], tp);
    }
    #pragma unroll
    for (int off = 32; off > 0; off >>= 1) {
        s += __shfl_xor(s, off);
        tp += __shfl_xor(tp, off);
    }
    if (lane == 0) {
        sq[row] = s;
        float u = tp + b_tau[0];
        float tau = 1.f / (1.f + expf(-u));
        float kf = rintf(16.f - 12.f * tau);
        int k = (int)kf;
        k = min(16, max(1, k));
        kk[row] = k;
    }
}

// ---------------- both weight transposes (fp32 [K][N] -> bf16 [N][K]) ----------------
__global__ void __launch_bounds__(256) transpose_bf16_kernel(
    const float* __restrict__ Wp, unsigned short* __restrict__ wpT,
    const float* __restrict__ Wr, unsigned short* __restrict__ wrT)
{
    int i = blockIdx.x * 256 + threadIdx.x;
    if (i < DDIM * HDIM) {
        int k = i / HDIM, n = i % HDIM;
        wpT[(size_t)n * DDIM + k] = rne_bf16(Wp[i]);
    } else {
        int j = i - DDIM * HDIM;
        if (j < HDIM * HDIM) {
            int k = j / HDIM, n = j % HDIM;
            wrT[(size_t)n * HDIM + k] = rne_bf16(Wr[j]);
        }
    }
}

// ---------------- MFMA bf16 GEMM: out = relu(A[M,K]@W + bias), W given as WT[n][k] ----------------
__global__ void __launch_bounds__(256) mfma_gemm_bias_relu_kernel(
    const unsigned short* __restrict__ A, const unsigned short* __restrict__ WT,
    const float* __restrict__ bias, float* __restrict__ out, int K)
{
    __shared__ unsigned short Abuf[128 * 32];
    __shared__ unsigned short Bbuf[128 * 32];

    const int tid = threadIdx.x;
    const int wave = tid >> 6;
    const int rowbase = blockIdx.x * 128;
    const int nbase = blockIdx.y * 128;
    const int lane = tid & 63;
    const int wr = (wave >> 1) * 64;
    const int wc = (wave & 1) * 64;
    const int m16 = lane & 15;
    const int kq = lane >> 4;

    const int er0 = tid >> 2;
    const int er1 = 64 + (tid >> 2);
    const int eko = tid & 3;

    f32x4 acc[4][4];
    #pragma unroll
    for (int a = 0; a < 4; ++a)
        #pragma unroll
        for (int b = 0; b < 4; ++b)
            acc[a][b] = (f32x4){0.f, 0.f, 0.f, 0.f};

    for (int kb = 0; kb < K / 32; ++kb) {
        const int k0 = kb * 32;
        __syncthreads();
        __builtin_amdgcn_global_load_lds(
            (const __attribute__((address_space(1))) void*)(A + (size_t)(rowbase + er0) * K + k0 + eko * 8),
            (__attribute__((address_space(3))) void*)((char*)Abuf + (wave * 64) * 16), 16, 0, 0);
        __builtin_amdgcn_global_load_lds(
            (const __attribute__((address_space(1))) void*)(A + (size_t)(rowbase + er1) * K + k0 + eko * 8),
            (__attribute__((address_space(3))) void*)((char*)Abuf + (256 + wave * 64) * 16), 16, 0, 0);
        __builtin_amdgcn_global_load_lds(
            (const __attribute__((address_space(1))) void*)(WT + (size_t)(nbase + er0) * K + k0 + eko * 8),
            (__attribute__((address_space(3))) void*)((char*)Bbuf + (wave * 64) * 16), 16, 0, 0);
        __builtin_amdgcn_global_load_lds(
            (const __attribute__((address_space(1))) void*)(WT + (size_t)(nbase + er1) * K + k0 + eko * 8),
            (__attribute__((address_space(3))) void*)((char*)Bbuf + (256 + wave * 64) * 16), 16, 0, 0);
        __syncthreads();

        bf16x8 af[4], bfr[4];
        #pragma unroll
        for (int s = 0; s < 4; ++s) {
            af[s]  = *(const bf16x8*)&Abuf[(wr + s * 16 + m16) * 32 + kq * 8];
            bfr[s] = *(const bf16x8*)&Bbuf[(wc + s * 16 + m16) * 32 + kq * 8];
        }
        #pragma unroll
        for (int si = 0; si < 4; ++si)
            #pragma unroll
            for (int sj = 0; sj < 4; ++sj)
                acc[si][sj] = __builtin_amdgcn_mfma_f32_16x16x32_bf16(
                    af[si], bfr[sj], acc[si][sj], 0, 0, 0);
    }

    #pragma unroll
    for (int sj = 0; sj < 4; ++sj) {
        int c = nbase + wc + sj * 16 + m16;
        float bc = bias[c];
        #pragma unroll
        for (int si = 0; si < 4; ++si) {
            int r = rowbase + wr + si * 16 + kq * 4;
            #pragma unroll
            for (int v = 0; v < 4; ++v)
                out[(size_t)(r + v) * HDIM + c] = fmaxf(acc[si][sj][v] + bc, 0.f);
        }
    }
}

// ---------------- MFMA bf16 Gram GEMM + fused per-tile top-8 screening ----------------
// R12 structure: single-buffered staging, full 128-row Dt (odd stride),
// 2 threads/row scan, 4 epilogue barriers. keys[row][tile][16].
__global__ void __launch_bounds__(256) dist_topk_kernel(
    const unsigned short* __restrict__ xb, const float* __restrict__ sq,
    unsigned int* __restrict__ keys)
{
    __shared__ unsigned short Abuf[128 * 32];                 // 8 KB
    __shared__ unsigned short Bbuf[128 * 32];                 // 8 KB
    __shared__ __align__(16) unsigned short Dt[128 * DSTR];   // 34.5 KB

    int t = blockIdx.x;
    int bi = (int)((sqrtf(8.f * (float)t + 1.f) - 1.f) * 0.5f);
    while ((bi + 1) * (bi + 2) / 2 <= t) ++bi;
    while (bi * (bi + 1) / 2 > t) --bi;
    int bj = t - bi * (bi + 1) / 2;

    const int tid = threadIdx.x;
    const int wave = tid >> 6;
    const int lane = tid & 63;
    const int rowbase = bi * 128;
    const int colbase = bj * 128;
    const int wr = (wave >> 1) * 64;
    const int wc = (wave & 1) * 64;
    const int m16 = lane & 15;
    const int kq = lane >> 4;

    const int er0 = tid >> 2;
    const int er1 = 64 + (tid >> 2);
    const int eko = tid & 3;

    f32x4 acc[4][4];
    #pragma unroll
    for (int a = 0; a < 4; ++a)
        #pragma unroll
        for (int b = 0; b < 4; ++b)
            acc[a][b] = (f32x4){0.f, 0.f, 0.f, 0.f};

    for (int kb = 0; kb < DDIM / 32; ++kb) {
        const int k0 = kb * 32;
        __syncthreads();
        __builtin_amdgcn_global_load_lds(
            (const __attribute__((address_space(1))) void*)(xb + (size_t)(rowbase + er0) * DDIM + k0 + eko * 8),
            (__attribute__((address_space(3))) void*)((char*)Abuf + (wave * 64) * 16), 16, 0, 0);
        __builtin_amdgcn_global_load_lds(
            (const __attribute__((address_space(1))) void*)(xb + (size_t)(rowbase + er1) * DDIM + k0 + eko * 8),
            (__attribute__((address_space(3))) void*)((char*)Abuf + (256 + wave * 64) * 16), 16, 0, 0);
        __builtin_amdgcn_global_load_lds(
            (const __attribute__((address_space(1))) void*)(xb + (size_t)(colbase + er0) * DDIM + k0 + eko * 8),
            (__attribute__((address_space(3))) void*)((char*)Bbuf + (wave * 64) * 16), 16, 0, 0);
        __builtin_amdgcn_global_load_lds(
            (const __attribute__((address_space(1))) void*)(xb + (size_t)(colbase + er1) * DDIM + k0 + eko * 8),
            (__attribute__((address_space(3))) void*)((char*)Bbuf + (256 + wave * 64) * 16), 16, 0, 0);
        __syncthreads();

        bf16x8 af[4], bfr[4];
        #pragma unroll
        for (int s = 0; s < 4; ++s) {
            af[s]  = *(const bf16x8*)&Abuf[(wr + s * 16 + m16) * 32 + kq * 8];
            bfr[s] = *(const bf16x8*)&Bbuf[(wc + s * 16 + m16) * 32 + kq * 8];
        }
        #pragma unroll
        for (int si = 0; si < 4; ++si)
            #pragma unroll
            for (int sj = 0; sj < 4; ++sj)
                acc[si][sj] = __builtin_amdgcn_mfma_f32_16x16x32_bf16(
                    af[si], bfr[sj], acc[si][sj], 0, 0, 0);
    }

    const int sr = tid >> 1;          // scan row in tile (0..127)
    const int seg = tid & 1;          // 64-col half

    // ==== pass 1: rows of bi-block ====
    {
        float sqc[4];
        #pragma unroll
        for (int sj = 0; sj < 4; ++sj) sqc[sj] = sq[colbase + wc + sj * 16 + m16];
        #pragma unroll
        for (int si = 0; si < 4; ++si)
            #pragma unroll
            for (int sj = 0; sj < 4; ++sj) {
                int r = wr + si * 16 + kq * 4;
                int c = wc + sj * 16 + m16;
                #pragma unroll
                for (int v = 0; v < 4; ++v)
                    Dt[(r + v) * DSTR + c] = map16f(sqc[sj] - 2.0f * acc[si][sj][v]);
            }
        __syncthreads();

        unsigned int s0 = 0xFFFFFFFFu, s1 = 0xFFFFFFFEu, s2 = 0xFFFFFFFDu, s3 = 0xFFFFFFFCu;
        unsigned int s4 = 0xFFFFFFFBu, s5 = 0xFFFFFFFAu, s6 = 0xFFFFFFF9u, s7 = 0xFFFFFFF8u;
        unsigned int m = 0xFFFFFFFFu;
        const unsigned short* rowp = &Dt[sr * DSTR + seg * 64];
        #pragma unroll
        for (int i = 0; i < 8; ++i) {
            u16x8 ch = *(const u16x8*)(rowp + i * 8);
            u16x4 g4 = __builtin_elementwise_min(
                __builtin_shufflevector(ch, ch, 0, 1, 2, 3),
                __builtin_shufflevector(ch, ch, 4, 5, 6, 7));
            u16x2 g2 = __builtin_elementwise_min(
                __builtin_shufflevector(g4, g4, 0, 1),
                __builtin_shufflevector(g4, g4, 2, 3));
            unsigned int gmin = umin_((unsigned int)g2[0], (unsigned int)g2[1]);
            if ((gmin << 13) < m) {
                int cb = colbase + seg * 64 + i * 8;
                #pragma unroll
                for (int e = 0; e < 8; ++e)
                    ins8(s0, s1, s2, s3, s4, s5, s6, s7, m,
                         ((unsigned int)ch[e] << 13) | (unsigned int)(cb + e));
            }
        }
        size_t kb = (size_t)(rowbase + sr) * 1024 + (size_t)bj * 16 + seg * 8;
        uint4 o0; o0.x = s0; o0.y = s1; o0.z = s2; o0.w = s3;
        uint4 o1; o1.x = s4; o1.y = s5; o1.z = s6; o1.w = s7;
        *(uint4*)&keys[kb] = o0;
        *(uint4*)&keys[kb + 4] = o1;
    }

    // ==== pass 2: rows of bj-block via transposed tile (off-diagonal only) ====
    if (bi != bj) {
        __syncthreads();
        #pragma unroll
        for (int si = 0; si < 4; ++si) {
            float4 sqr4 = *(const float4*)&sq[rowbase + wr + si * 16 + kq * 4];
            float srw[4] = {sqr4.x, sqr4.y, sqr4.z, sqr4.w};
            #pragma unroll
            for (int sj = 0; sj < 4; ++sj) {
                int r = wr + si * 16 + kq * 4;
                int c = wc + sj * 16 + m16;
                unsigned short h4[4];
                #pragma unroll
                for (int v = 0; v < 4; ++v)
                    h4[v] = map16f(srw[v] - 2.0f * acc[si][sj][v]);
                *(unsigned long long*)&Dt[c * DSTR + r] = *(unsigned long long*)h4;
            }
        }
        __syncthreads();

        unsigned int s0 = 0xFFFFFFFFu, s1 = 0xFFFFFFFEu, s2 = 0xFFFFFFFDu, s3 = 0xFFFFFFFCu;
        unsigned int s4 = 0xFFFFFFFBu, s5 = 0xFFFFFFFAu, s6 = 0xFFFFFFF9u, s7 = 0xFFFFFFF8u;
        unsigned int m = 0xFFFFFFFFu;
        const unsigned short* rowp = &Dt[sr * DSTR + seg * 64];
        #pragma unroll
        for (int i = 0; i < 8; ++i) {
            u16x8 ch = *(const u16x8*)(rowp + i * 8);
            u16x4 g4 = __builtin_elementwise_min(
                __builtin_shufflevector(ch, ch, 0, 1, 2, 3),
                __builtin_shufflevector(ch, ch, 4, 5, 6, 7));
            u16x2 g2 = __builtin_elementwise_min(
                __builtin_shufflevector(g4, g4, 0, 1),
                __builtin_shufflevector(g4, g4, 2, 3));
            unsigned int gmin = umin_((unsigned int)g2[0], (unsigned int)g2[1]);
            if ((gmin << 13) < m) {
                int cb = rowbase + seg * 64 + i * 8;
                #pragma unroll
                for (int e = 0; e < 8; ++e)
                    ins8(s0, s1, s2, s3, s4, s5, s6, s7, m,
                         ((unsigned int)ch[e] << 13) | (unsigned int)(cb + e));
            }
        }
        size_t kb = (size_t)(colbase + sr) * 1024 + (size_t)bi * 16 + seg * 8;
        uint4 o0; o0.x = s0; o0.y = s1; o0.z = s2; o0.w = s3;
        uint4 o1; o1.x = s4; o1.y = s5; o1.z = s6; o1.w = s7;
        *(uint4*)&keys[kb] = o0;
        *(uint4*)&keys[kb + 4] = o1;
    }
}

// ---------------- merge per-tile keys -> top-32 candidates (1 wave / row) ----------------
__global__ void __launch_bounds__(256) select_merge_kernel(
    const unsigned int* __restrict__ keys, int* __restrict__ cand)
{
    const int row = blockIdx.x * 4 + (threadIdx.x >> 6);
    const int lane = threadIdx.x & 63;
    const uint4* kp = (const uint4*)(keys + (size_t)row * 1024 + lane * 16);

    unsigned int s0 = 0xFFFFFFFFu, s1 = 0xFFFFFFFEu, s2 = 0xFFFFFFFDu, s3 = 0xFFFFFFFCu;
    unsigned int s4 = 0xFFFFFFFBu, s5 = 0xFFFFFFFAu, s6 = 0xFFFFFFF9u, s7 = 0xFFFFFFF8u;
    unsigned int m = 0xFFFFFFFFu;

    #pragma unroll
    for (int q = 0; q < 4; ++q) {
        uint4 v = kp[q];
        unsigned int gmin = umin_(umin_(v.x, v.y), umin_(v.z, v.w));
        if (gmin < m) {
            ins8(s0, s1, s2, s3, s4, s5, s6, s7, m, v.x);
            ins8(s0, s1, s2, s3, s4, s5, s6, s7, m, v.y);
            ins8(s0, s1, s2, s3, s4, s5, s6, s7, m, v.z);
            ins8(s0, s1, s2, s3, s4, s5, s6, s7, m, v.w);
        }
    }

    unsigned int lmin = umin_(umin_(umin_(s0, s1), umin_(s2, s3)),
                              umin_(umin_(s4, s5), umin_(s6, s7)));
    unsigned int myout = 0;
    for (int t = 0; t < 32; ++t) {
        unsigned int w = lmin;
        #pragma unroll
        for (int off = 32; off > 0; off >>= 1)
            w = umin_(w, (unsigned int)__shfl_xor((int)w, off));
        if (lane == t) myout = w;
        if (lmin == w) {
            s0 = (s0 == w) ? 0xFFFFFFFFu : s0;
            s1 = (s1 == w) ? 0xFFFFFFFFu : s1;
            s2 = (s2 == w) ? 0xFFFFFFFFu : s2;
            s3 = (s3 == w) ? 0xFFFFFFFFu : s3;
            s4 = (s4 == w) ? 0xFFFFFFFFu : s4;
            s5 = (s5 == w) ? 0xFFFFFFFFu : s5;
            s6 = (s6 == w) ? 0xFFFFFFFFu : s6;
            s7 = (s7 == w) ? 0xFFFFFFFFu : s7;
            lmin = umin_(umin_(umin_(s0, s1), umin_(s2, s3)),
                         umin_(umin_(s4, s5), umin_(s6, s7)));
        }
    }
    if (lane < 32)
        cand[(size_t)row * 32 + lane] = (int)(myout & 8191u);
}

// ---------------- exact fp32 rescore -> top-16, fused with gather-mean agg ----------------
__global__ void __launch_bounds__(256) rescore_agg_kernel(
    const float* __restrict__ x, const float* __restrict__ sq,
    const int* __restrict__ cand, const int* __restrict__ kk,
    const float* __restrict__ h, unsigned short* __restrict__ aggb)
{
    const int w = threadIdx.x >> 6;
    const int row = blockIdx.x * 4 + w;
    const int lane = threadIdx.x & 63;
    __shared__ int sidx[4][16];

    float xr[6];
    #pragma unroll
    for (int q = 0; q < 6; ++q) xr[q] = x[(size_t)row * DDIM + lane + 64 * q];
    int myj = cand[(size_t)row * 32 + (lane & 31)];
    float sqrow = sq[row];
    float myd = 0.f;
    for (int c = 0; c < 32; ++c) {
        int j = __shfl(myj, c);
        const float* xc = x + (size_t)j * DDIM;
        float p = 0.f;
        #pragma unroll
        for (int q = 0; q < 6; ++q) p = fmaf(xr[q], xc[lane + 64 * q], p);
        #pragma unroll
        for (int off = 32; off > 0; off >>= 1) p += __shfl_xor(p, off);
        float d = sqrow + sq[j] - 2.f * p;
        if (lane == c) myd = d;
    }
    int rank = 0;
    for (int t = 0; t < 32; ++t) {
        float dt = __shfl(myd, t); int jt = __shfl(myj, t);
        if (dj_better(dt, jt, myd, myj)) ++rank;
    }
    if (lane < 32 && rank < 16) sidx[w][rank] = myj;
    __syncthreads();

    // gather-mean of first k neighbors' h rows (4 fp32 chunks per lane)
    int k = kk[row];
    float a0 = 0.f, a1 = 0.f, a2 = 0.f, a3 = 0.f;
    for (int t = 0; t < k; ++t) {
        const float* hr = h + (size_t)sidx[w][t] * HDIM;
        a0 += hr[lane];
        a1 += hr[lane + 64];
        a2 += hr[lane + 128];
        a3 += hr[lane + 192];
    }
    float inv = 1.f / (float)k;
    unsigned short* ar = aggb + (size_t)row * HDIM;
    ar[lane]       = rne_bf16(a0 * inv);
    ar[lane + 64]  = rne_bf16(a1 * inv);
    ar[lane + 128] = rne_bf16(a2 * inv);
    ar[lane + 192] = rne_bf16(a3 * inv);
}

// ---------------- LayerNorm(h + r) * g + b, then @ W_fc + b_fc ----------------
__global__ void __launch_bounds__(256) ln_fc_kernel(
    const float* __restrict__ h, const float* __restrict__ r,
    const float* __restrict__ g, const float* __restrict__ bb,
    const float* __restrict__ W_fc, const float* __restrict__ b_fc,
    float* __restrict__ out)
{
    int row = blockIdx.x, tid = threadIdx.x;
    int wave = tid >> 6, lane = tid & 63;
    float z = h[(size_t)row * HDIM + tid] + r[(size_t)row * HDIM + tid];
    float s = z, s2 = z * z;
    #pragma unroll
    for (int off = 32; off > 0; off >>= 1) { s += __shfl_xor(s, off); s2 += __shfl_xor(s2, off); }
    __shared__ float red[8];
    __shared__ float smv[2];
    if (lane == 0) { red[wave] = s; red[4 + wave] = s2; }
    __syncthreads();
    if (tid == 0) {
        float ts = red[0] + red[1] + red[2] + red[3];
        float t2 = red[4] + red[5] + red[6] + red[7];
        float mu = ts / 256.f;
        float var = t2 / 256.f - mu * mu;
        smv[0] = mu; smv[1] = rsqrtf(var + LN_EPS);
    }
    __syncthreads();
    float zn = (z - smv[0]) * smv[1];
    float val = zn * g[tid] + bb[tid];
    float p[6];
    #pragma unroll
    for (int c = 0; c < 6; ++c) p[c] = val * W_fc[tid * 6 + c];
    #pragma unroll
    for (int c = 0; c < 6; ++c)
        #pragma unroll
        for (int off = 32; off > 0; off >>= 1) p[c] += __shfl_xor(p[c], off);
    __shared__ float pr[4][6];
    if (lane == 0) {
        #pragma unroll
        for (int c = 0; c < 6; ++c) pr[wave][c] = p[c];
    }
    __syncthreads();
    if (tid < 6)
        out[(size_t)row * CDIM + tid] = pr[0][tid] + pr[1][tid] + pr[2][tid] + pr[3][tid] + b_fc[tid];
}

extern "C" void kernel_launch(void* const* d_in, const int* in_sizes, int n_in,
                              void* d_out, int out_size, void* d_ws, size_t ws_size,
                              hipStream_t stream) {
    const float* x      = (const float*)d_in[0];
    const float* W_proj = (const float*)d_in[1];
    const float* b_proj = (const float*)d_in[2];
    const float* W_tau  = (const float*)d_in[3];
    const float* b_tau  = (const float*)d_in[4];
    const float* W_res  = (const float*)d_in[5];
    const float* b_res  = (const float*)d_in[6];
    const float* ln_g   = (const float*)d_in[7];
    const float* ln_b   = (const float*)d_in[8];
    const float* W_fc   = (const float*)d_in[9];
    const float* b_fc   = (const float*)d_in[10];
    float* out = (float*)d_out;

    char* ws = (char*)d_ws;
    float* sq   = (float*)ws;                        ws += (size_t)NROWS * 4;
    int*   kk   = (int*)ws;                          ws += (size_t)NROWS * 4;
    float* h    = (float*)ws;                        ws += (size_t)NROWS * HDIM * 4;
    float* r    = (float*)ws;                        ws += (size_t)NROWS * HDIM * 4;
    int*   cand = (int*)ws;                          ws += (size_t)NROWS * 32 * 4;
    unsigned short* xb   = (unsigned short*)ws;      ws += (size_t)NROWS * DDIM * 2;
    unsigned short* aggb = (unsigned short*)ws;      ws += (size_t)NROWS * HDIM * 2;
    unsigned short* wpT  = (unsigned short*)ws;      ws += (size_t)DDIM * HDIM * 2;
    unsigned short* wrT  = (unsigned short*)ws;      ws += (size_t)HDIM * HDIM * 2;
    ws = (char*)(((size_t)ws + 255) & ~(size_t)255);
    unsigned int* keys = (unsigned int*)ws;          ws += (size_t)NROWS * 1024 * 4;   // 32 MB

    precompute_kernel<<<NROWS / 4, 256, 0, stream>>>(x, W_tau, b_tau, xb, sq, kk);
    transpose_bf16_kernel<<<(DDIM * HDIM + HDIM * HDIM + 255) / 256, 256, 0, stream>>>(
        W_proj, wpT, W_res, wrT);
    mfma_gemm_bias_relu_kernel<<<dim3(NROWS / 128, HDIM / 128), 256, 0, stream>>>(
        xb, wpT, b_proj, h, DDIM);
    dist_topk_kernel<<<(NROWS/128) * (NROWS/128 + 1) / 2, 256, 0, stream>>>(xb, sq, keys);
    select_merge_kernel<<<NROWS / 4, 256, 0, stream>>>(keys, cand);
    rescore_agg_kernel<<<NROWS / 4, 256, 0, stream>>>(x, sq, cand, kk, h, aggb);
    mfma_gemm_bias_relu_kernel<<<dim3(NROWS / 128, HDIM / 128), 256, 0, stream>>>(
        aggb, wrT, b_res, r, HDIM);
    ln_fc_kernel<<<NROWS, 256, 0, stream>>>(h, r, ln_g, ln_b, W_fc, b_fc, out);
}

// Round 15
// 253.801 us; speedup vs baseline: 1.1525x; 1.0918x over previous
//
#include <hip/hip_runtime.h>
#include <hip/hip_fp16.h>
#include <math.h>

#define NROWS 8192
#define DDIM 384
#define HDIM 256
#define CDIM 6
#define LN_EPS 1e-5f
#define DSTR 138   // Dt row stride in halves (69 dwords, odd -> conflict-free scan)

typedef short bf16x8 __attribute__((ext_vector_type(8)));
typedef float f32x4 __attribute__((ext_vector_type(4)));
typedef unsigned short u16x8 __attribute__((ext_vector_type(8)));
typedef unsigned short u16x4 __attribute__((ext_vector_type(4)));
typedef unsigned short u16x2 __attribute__((ext_vector_type(2)));

__device__ __forceinline__ bool dj_better(float d1, int j1, float d2, int j2) {
    return (d1 < d2) || (d1 == d2 && j1 < j2);
}

__device__ __forceinline__ unsigned int umin_(unsigned int a, unsigned int b) { return a < b ? a : b; }
__device__ __forceinline__ unsigned int umax_(unsigned int a, unsigned int b) { return a > b ? a : b; }

// fp32 -> fp16 -> monotonic u16 (unsigned order == float order)
__device__ __forceinline__ unsigned short map16f(float v) {
    union { _Float16 f; unsigned short u; } c;
    c.f = (_Float16)v;
    unsigned short b = c.u;
    return (unsigned short)(b ^ (unsigned short)((((short)b) >> 15) | 0x8000));
}

__device__ __forceinline__ unsigned short rne_bf16(float v) {
    unsigned int u = __float_as_uint(v);
    u += 0x7fffu + ((u >> 16) & 1u);
    return (unsigned short)(u >> 16);
}

// branchless unsorted 8-slot top-8 insert (replace current max, recompute max)
__device__ __forceinline__ void ins8(
    unsigned int& s0, unsigned int& s1, unsigned int& s2, unsigned int& s3,
    unsigned int& s4, unsigned int& s5, unsigned int& s6, unsigned int& s7,
    unsigned int& m, unsigned int key)
{
    if (key < m) {
        s0 = (s0 == m) ? key : s0;
        s1 = (s1 == m) ? key : s1;
        s2 = (s2 == m) ? key : s2;
        s3 = (s3 == m) ? key : s3;
        s4 = (s4 == m) ? key : s4;
        s5 = (s5 == m) ? key : s5;
        s6 = (s6 == m) ? key : s6;
        s7 = (s7 == m) ? key : s7;
        m = umax_(umax_(umax_(s0, s1), umax_(s2, s3)),
                  umax_(umax_(s4, s5), umax_(s6, s7)));
    }
}

// ---------------- fused prep: xb/sq/kk (blocks 0..2047) + weight transposes ----------------
__global__ void __launch_bounds__(256) prep_kernel(
    const float* __restrict__ x, const float* __restrict__ W_tau,
    const float* __restrict__ b_tau, unsigned short* __restrict__ xb,
    float* __restrict__ sq, int* __restrict__ kk,
    const float* __restrict__ Wp, unsigned short* __restrict__ wpT,
    const float* __restrict__ Wr, unsigned short* __restrict__ wrT)
{
    int tid = threadIdx.x;
    if (blockIdx.x < NROWS / 4) {
        int wave = tid >> 6, lane = tid & 63;
        int row = blockIdx.x * 4 + wave;
        const float* xr = x + (size_t)row * DDIM;
        unsigned short* xbr = xb + (size_t)row * DDIM;
        float s = 0.f, tp = 0.f;
        #pragma unroll
        for (int q = 0; q < 6; ++q) {
            float v = xr[lane + 64 * q];
            xbr[lane + 64 * q] = rne_bf16(v);
            s = fmaf(v, v, s);
            tp = fmaf(v, W_tau[lane + 64 * q], tp);
        }
        #pragma unroll
        for (int off = 32; off > 0; off >>= 1) {
            s += __shfl_xor(s, off);
            tp += __shfl_xor(tp, off);
        }
        if (lane == 0) {
            sq[row] = s;
            float u = tp + b_tau[0];
            float tau = 1.f / (1.f + expf(-u));
            float kf = rintf(16.f - 12.f * tau);
            int k = (int)kf;
            k = min(16, max(1, k));
            kk[row] = k;
        }
    } else {
        int i = (blockIdx.x - NROWS / 4) * 256 + tid;
        if (i < DDIM * HDIM) {
            int k = i / HDIM, n = i % HDIM;
            wpT[(size_t)n * DDIM + k] = rne_bf16(Wp[i]);
        } else {
            int j = i - DDIM * HDIM;
            if (j < HDIM * HDIM) {
                int k = j / HDIM, n = j % HDIM;
                wrT[(size_t)n * HDIM + k] = rne_bf16(Wr[j]);
            }
        }
    }
}

// ---------------- MFMA bf16 GEMM: out = relu(A[M,K]@W + bias), W given as WT[n][k] ----------------
__global__ void __launch_bounds__(256) mfma_gemm_bias_relu_kernel(
    const unsigned short* __restrict__ A, const unsigned short* __restrict__ WT,
    const float* __restrict__ bias, float* __restrict__ out, int K)
{
    __shared__ unsigned short Abuf[128 * 32];
    __shared__ unsigned short Bbuf[128 * 32];

    const int tid = threadIdx.x;
    const int wave = tid >> 6;
    const int rowbase = blockIdx.x * 128;
    const int nbase = blockIdx.y * 128;
    const int lane = tid & 63;
    const int wr = (wave >> 1) * 64;
    const int wc = (wave & 1) * 64;
    const int m16 = lane & 15;
    const int kq = lane >> 4;

    const int er0 = tid >> 2;
    const int er1 = 64 + (tid >> 2);
    const int eko = tid & 3;

    f32x4 acc[4][4];
    #pragma unroll
    for (int a = 0; a < 4; ++a)
        #pragma unroll
        for (int b = 0; b < 4; ++b)
            acc[a][b] = (f32x4){0.f, 0.f, 0.f, 0.f};

    for (int kb = 0; kb < K / 32; ++kb) {
        const int k0 = kb * 32;
        __syncthreads();
        __builtin_amdgcn_global_load_lds(
            (const __attribute__((address_space(1))) void*)(A + (size_t)(rowbase + er0) * K + k0 + eko * 8),
            (__attribute__((address_space(3))) void*)((char*)Abuf + (wave * 64) * 16), 16, 0, 0);
        __builtin_amdgcn_global_load_lds(
            (const __attribute__((address_space(1))) void*)(A + (size_t)(rowbase + er1) * K + k0 + eko * 8),
            (__attribute__((address_space(3))) void*)((char*)Abuf + (256 + wave * 64) * 16), 16, 0, 0);
        __builtin_amdgcn_global_load_lds(
            (const __attribute__((address_space(1))) void*)(WT + (size_t)(nbase + er0) * K + k0 + eko * 8),
            (__attribute__((address_space(3))) void*)((char*)Bbuf + (wave * 64) * 16), 16, 0, 0);
        __builtin_amdgcn_global_load_lds(
            (const __attribute__((address_space(1))) void*)(WT + (size_t)(nbase + er1) * K + k0 + eko * 8),
            (__attribute__((address_space(3))) void*)((char*)Bbuf + (256 + wave * 64) * 16), 16, 0, 0);
        __syncthreads();

        bf16x8 af[4], bfr[4];
        #pragma unroll
        for (int s = 0; s < 4; ++s) {
            af[s]  = *(const bf16x8*)&Abuf[(wr + s * 16 + m16) * 32 + kq * 8];
            bfr[s] = *(const bf16x8*)&Bbuf[(wc + s * 16 + m16) * 32 + kq * 8];
        }
        #pragma unroll
        for (int si = 0; si < 4; ++si)
            #pragma unroll
            for (int sj = 0; sj < 4; ++sj)
                acc[si][sj] = __builtin_amdgcn_mfma_f32_16x16x32_bf16(
                    af[si], bfr[sj], acc[si][sj], 0, 0, 0);
    }

    #pragma unroll
    for (int sj = 0; sj < 4; ++sj) {
        int c = nbase + wc + sj * 16 + m16;
        float bc = bias[c];
        #pragma unroll
        for (int si = 0; si < 4; ++si) {
            int r = rowbase + wr + si * 16 + kq * 4;
            #pragma unroll
            for (int v = 0; v < 4; ++v)
                out[(size_t)(r + v) * HDIM + c] = fmaxf(acc[si][sj][v] + bc, 0.f);
        }
    }
}

// ---------------- MFMA bf16 Gram GEMM + fused per-tile top-8 screening ----------------
// Single-buffered staging, full 128-row Dt (odd stride), 2 threads/row scan,
// 4 epilogue barriers. keys[row][tile][16].
__global__ void __launch_bounds__(256) dist_topk_kernel(
    const unsigned short* __restrict__ xb, const float* __restrict__ sq,
    unsigned int* __restrict__ keys)
{
    __shared__ unsigned short Abuf[128 * 32];                 // 8 KB
    __shared__ unsigned short Bbuf[128 * 32];                 // 8 KB
    __shared__ __align__(16) unsigned short Dt[128 * DSTR];   // 34.5 KB

    int t = blockIdx.x;
    int bi = (int)((sqrtf(8.f * (float)t + 1.f) - 1.f) * 0.5f);
    while ((bi + 1) * (bi + 2) / 2 <= t) ++bi;
    while (bi * (bi + 1) / 2 > t) --bi;
    int bj = t - bi * (bi + 1) / 2;

    const int tid = threadIdx.x;
    const int wave = tid >> 6;
    const int lane = tid & 63;
    const int rowbase = bi * 128;
    const int colbase = bj * 128;
    const int wr = (wave >> 1) * 64;
    const int wc = (wave & 1) * 64;
    const int m16 = lane & 15;
    const int kq = lane >> 4;

    const int er0 = tid >> 2;
    const int er1 = 64 + (tid >> 2);
    const int eko = tid & 3;

    f32x4 acc[4][4];
    #pragma unroll
    for (int a = 0; a < 4; ++a)
        #pragma unroll
        for (int b = 0; b < 4; ++b)
            acc[a][b] = (f32x4){0.f, 0.f, 0.f, 0.f};

    for (int kb = 0; kb < DDIM / 32; ++kb) {
        const int k0 = kb * 32;
        __syncthreads();
        __builtin_amdgcn_global_load_lds(
            (const __attribute__((address_space(1))) void*)(xb + (size_t)(rowbase + er0) * DDIM + k0 + eko * 8),
            (__attribute__((address_space(3))) void*)((char*)Abuf + (wave * 64) * 16), 16, 0, 0);
        __builtin_amdgcn_global_load_lds(
            (const __attribute__((address_space(1))) void*)(xb + (size_t)(rowbase + er1) * DDIM + k0 + eko * 8),
            (__attribute__((address_space(3))) void*)((char*)Abuf + (256 + wave * 64) * 16), 16, 0, 0);
        __builtin_amdgcn_global_load_lds(
            (const __attribute__((address_space(1))) void*)(xb + (size_t)(colbase + er0) * DDIM + k0 + eko * 8),
            (__attribute__((address_space(3))) void*)((char*)Bbuf + (wave * 64) * 16), 16, 0, 0);
        __builtin_amdgcn_global_load_lds(
            (const __attribute__((address_space(1))) void*)(xb + (size_t)(colbase + er1) * DDIM + k0 + eko * 8),
            (__attribute__((address_space(3))) void*)((char*)Bbuf + (256 + wave * 64) * 16), 16, 0, 0);
        __syncthreads();

        bf16x8 af[4], bfr[4];
        #pragma unroll
        for (int s = 0; s < 4; ++s) {
            af[s]  = *(const bf16x8*)&Abuf[(wr + s * 16 + m16) * 32 + kq * 8];
            bfr[s] = *(const bf16x8*)&Bbuf[(wc + s * 16 + m16) * 32 + kq * 8];
        }
        #pragma unroll
        for (int si = 0; si < 4; ++si)
            #pragma unroll
            for (int sj = 0; sj < 4; ++sj)
                acc[si][sj] = __builtin_amdgcn_mfma_f32_16x16x32_bf16(
                    af[si], bfr[sj], acc[si][sj], 0, 0, 0);
    }

    const int sr = tid >> 1;          // scan row in tile (0..127)
    const int seg = tid & 1;          // 64-col half

    // ==== pass 1: rows of bi-block ====
    {
        float sqc[4];
        #pragma unroll
        for (int sj = 0; sj < 4; ++sj) sqc[sj] = sq[colbase + wc + sj * 16 + m16];
        #pragma unroll
        for (int si = 0; si < 4; ++si)
            #pragma unroll
            for (int sj = 0; sj < 4; ++sj) {
                int r = wr + si * 16 + kq * 4;
                int c = wc + sj * 16 + m16;
                #pragma unroll
                for (int v = 0; v < 4; ++v)
                    Dt[(r + v) * DSTR + c] = map16f(sqc[sj] - 2.0f * acc[si][sj][v]);
            }
        __syncthreads();

        unsigned int s0 = 0xFFFFFFFFu, s1 = 0xFFFFFFFEu, s2 = 0xFFFFFFFDu, s3 = 0xFFFFFFFCu;
        unsigned int s4 = 0xFFFFFFFBu, s5 = 0xFFFFFFFAu, s6 = 0xFFFFFFF9u, s7 = 0xFFFFFFF8u;
        unsigned int m = 0xFFFFFFFFu;
        const unsigned short* rowp = &Dt[sr * DSTR + seg * 64];
        #pragma unroll
        for (int i = 0; i < 8; ++i) {
            u16x8 ch = *(const u16x8*)(rowp + i * 8);
            u16x4 g4 = __builtin_elementwise_min(
                __builtin_shufflevector(ch, ch, 0, 1, 2, 3),
                __builtin_shufflevector(ch, ch, 4, 5, 6, 7));
            u16x2 g2 = __builtin_elementwise_min(
                __builtin_shufflevector(g4, g4, 0, 1),
                __builtin_shufflevector(g4, g4, 2, 3));
            unsigned int gmin = umin_((unsigned int)g2[0], (unsigned int)g2[1]);
            if ((gmin << 13) < m) {
                int cb = colbase + seg * 64 + i * 8;
                #pragma unroll
                for (int e = 0; e < 8; ++e)
                    ins8(s0, s1, s2, s3, s4, s5, s6, s7, m,
                         ((unsigned int)ch[e] << 13) | (unsigned int)(cb + e));
            }
        }
        size_t kb = (size_t)(rowbase + sr) * 1024 + (size_t)bj * 16 + seg * 8;
        uint4 o0; o0.x = s0; o0.y = s1; o0.z = s2; o0.w = s3;
        uint4 o1; o1.x = s4; o1.y = s5; o1.z = s6; o1.w = s7;
        *(uint4*)&keys[kb] = o0;
        *(uint4*)&keys[kb + 4] = o1;
    }

    // ==== pass 2: rows of bj-block via transposed tile (off-diagonal only) ====
    if (bi != bj) {
        __syncthreads();
        #pragma unroll
        for (int si = 0; si < 4; ++si) {
            float4 sqr4 = *(const float4*)&sq[rowbase + wr + si * 16 + kq * 4];
            float srw[4] = {sqr4.x, sqr4.y, sqr4.z, sqr4.w};
            #pragma unroll
            for (int sj = 0; sj < 4; ++sj) {
                int r = wr + si * 16 + kq * 4;
                int c = wc + sj * 16 + m16;
                unsigned short h4[4];
                #pragma unroll
                for (int v = 0; v < 4; ++v)
                    h4[v] = map16f(srw[v] - 2.0f * acc[si][sj][v]);
                *(unsigned long long*)&Dt[c * DSTR + r] = *(unsigned long long*)h4;
            }
        }
        __syncthreads();

        unsigned int s0 = 0xFFFFFFFFu, s1 = 0xFFFFFFFEu, s2 = 0xFFFFFFFDu, s3 = 0xFFFFFFFCu;
        unsigned int s4 = 0xFFFFFFFBu, s5 = 0xFFFFFFFAu, s6 = 0xFFFFFFF9u, s7 = 0xFFFFFFF8u;
        unsigned int m = 0xFFFFFFFFu;
        const unsigned short* rowp = &Dt[sr * DSTR + seg * 64];
        #pragma unroll
        for (int i = 0; i < 8; ++i) {
            u16x8 ch = *(const u16x8*)(rowp + i * 8);
            u16x4 g4 = __builtin_elementwise_min(
                __builtin_shufflevector(ch, ch, 0, 1, 2, 3),
                __builtin_shufflevector(ch, ch, 4, 5, 6, 7));
            u16x2 g2 = __builtin_elementwise_min(
                __builtin_shufflevector(g4, g4, 0, 1),
                __builtin_shufflevector(g4, g4, 2, 3));
            unsigned int gmin = umin_((unsigned int)g2[0], (unsigned int)g2[1]);
            if ((gmin << 13) < m) {
                int cb = rowbase + seg * 64 + i * 8;
                #pragma unroll
                for (int e = 0; e < 8; ++e)
                    ins8(s0, s1, s2, s3, s4, s5, s6, s7, m,
                         ((unsigned int)ch[e] << 13) | (unsigned int)(cb + e));
            }
        }
        size_t kb = (size_t)(colbase + sr) * 1024 + (size_t)bi * 16 + seg * 8;
        uint4 o0; o0.x = s0; o0.y = s1; o0.z = s2; o0.w = s3;
        uint4 o1; o1.x = s4; o1.y = s5; o1.z = s6; o1.w = s7;
        *(uint4*)&keys[kb] = o0;
        *(uint4*)&keys[kb + 4] = o1;
    }
}

// ---------------- fused: merge keys -> top-32, exact fp32 rescore -> top-16, gather-mean ----------------
// One wave per row; no cand round-trip.
__global__ void __launch_bounds__(256) topk_rescore_agg_kernel(
    const unsigned int* __restrict__ keys, const float* __restrict__ x,
    const float* __restrict__ sq, const int* __restrict__ kk,
    const float* __restrict__ h, unsigned short* __restrict__ aggb)
{
    const int w = threadIdx.x >> 6;
    const int row = blockIdx.x * 4 + w;
    const int lane = threadIdx.x & 63;
    __shared__ int sidx[4][16];

    // -- phase 1: merge 64x16 per-tile keys -> wave top-32 (unique integer keys) --
    const uint4* kp = (const uint4*)(keys + (size_t)row * 1024 + lane * 16);
    unsigned int s0 = 0xFFFFFFFFu, s1 = 0xFFFFFFFEu, s2 = 0xFFFFFFFDu, s3 = 0xFFFFFFFCu;
    unsigned int s4 = 0xFFFFFFFBu, s5 = 0xFFFFFFFAu, s6 = 0xFFFFFFF9u, s7 = 0xFFFFFFF8u;
    unsigned int m = 0xFFFFFFFFu;
    #pragma unroll
    for (int q = 0; q < 4; ++q) {
        uint4 v = kp[q];
        unsigned int gmin = umin_(umin_(v.x, v.y), umin_(v.z, v.w));
        if (gmin < m) {
            ins8(s0, s1, s2, s3, s4, s5, s6, s7, m, v.x);
            ins8(s0, s1, s2, s3, s4, s5, s6, s7, m, v.y);
            ins8(s0, s1, s2, s3, s4, s5, s6, s7, m, v.z);
            ins8(s0, s1, s2, s3, s4, s5, s6, s7, m, v.w);
        }
    }
    unsigned int lmin = umin_(umin_(umin_(s0, s1), umin_(s2, s3)),
                              umin_(umin_(s4, s5), umin_(s6, s7)));
    unsigned int myout = 0;
    for (int t = 0; t < 32; ++t) {
        unsigned int wv = lmin;
        #pragma unroll
        for (int off = 32; off > 0; off >>= 1)
            wv = umin_(wv, (unsigned int)__shfl_xor((int)wv, off));
        if (lane == t) myout = wv;
        if (lmin == wv) {
            s0 = (s0 == wv) ? 0xFFFFFFFFu : s0;
            s1 = (s1 == wv) ? 0xFFFFFFFFu : s1;
            s2 = (s2 == wv) ? 0xFFFFFFFFu : s2;
            s3 = (s3 == wv) ? 0xFFFFFFFFu : s3;
            s4 = (s4 == wv) ? 0xFFFFFFFFu : s4;
            s5 = (s5 == wv) ? 0xFFFFFFFFu : s5;
            s6 = (s6 == wv) ? 0xFFFFFFFFu : s6;
            s7 = (s7 == wv) ? 0xFFFFFFFFu : s7;
            lmin = umin_(umin_(umin_(s0, s1), umin_(s2, s3)),
                         umin_(umin_(s4, s5), umin_(s6, s7)));
        }
    }
    // candidate j for this lane (lanes 32-63 mirror 0-31)
    int myj = __shfl((int)(myout & 8191u), lane & 31);

    // -- phase 2: exact fp32 rescore with reference tie-break --
    float xr[6];
    #pragma unroll
    for (int q = 0; q < 6; ++q) xr[q] = x[(size_t)row * DDIM + lane + 64 * q];
    float sqrow = sq[row];
    float myd = 0.f;
    for (int c = 0; c < 32; ++c) {
        int j = __shfl(myj, c);
        const float* xc = x + (size_t)j * DDIM;
        float p = 0.f;
        #pragma unroll
        for (int q = 0; q < 6; ++q) p = fmaf(xr[q], xc[lane + 64 * q], p);
        #pragma unroll
        for (int off = 32; off > 0; off >>= 1) p += __shfl_xor(p, off);
        float d = sqrow + sq[j] - 2.f * p;
        if (lane == c) myd = d;
    }
    int rank = 0;
    for (int t = 0; t < 32; ++t) {
        float dt = __shfl(myd, t); int jt = __shfl(myj, t);
        if (dj_better(dt, jt, myd, myj)) ++rank;
    }
    if (lane < 32 && rank < 16) sidx[w][rank] = myj;
    __syncthreads();

    // -- phase 3: gather-mean of first k neighbors' h rows --
    int k = kk[row];
    float a0 = 0.f, a1 = 0.f, a2 = 0.f, a3 = 0.f;
    for (int t = 0; t < k; ++t) {
        const float* hr = h + (size_t)sidx[w][t] * HDIM;
        a0 += hr[lane];
        a1 += hr[lane + 64];
        a2 += hr[lane + 128];
        a3 += hr[lane + 192];
    }
    float inv = 1.f / (float)k;
    unsigned short* ar = aggb + (size_t)row * HDIM;
    ar[lane]       = rne_bf16(a0 * inv);
    ar[lane + 64]  = rne_bf16(a1 * inv);
    ar[lane + 128] = rne_bf16(a2 * inv);
    ar[lane + 192] = rne_bf16(a3 * inv);
}

// ---------------- LayerNorm(h + r) * g + b, then @ W_fc + b_fc (one row per wave) ----------------
__global__ void __launch_bounds__(256) ln_fc_kernel(
    const float* __restrict__ h, const float* __restrict__ r,
    const float* __restrict__ g, const float* __restrict__ bb,
    const float* __restrict__ W_fc, const float* __restrict__ b_fc,
    float* __restrict__ out)
{
    const int row = blockIdx.x * 4 + (threadIdx.x >> 6);
    const int lane = threadIdx.x & 63;
    const float* hp = h + (size_t)row * HDIM;
    const float* rp = r + (size_t)row * HDIM;

    float z[4];
    #pragma unroll
    for (int q = 0; q < 4; ++q)
        z[q] = hp[lane + 64 * q] + rp[lane + 64 * q];

    float s = z[0] + z[1] + z[2] + z[3];
    float s2 = z[0]*z[0] + z[1]*z[1] + z[2]*z[2] + z[3]*z[3];
    #pragma unroll
    for (int off = 32; off > 0; off >>= 1) {
        s += __shfl_xor(s, off);
        s2 += __shfl_xor(s2, off);
    }
    float mu = s / 256.f;
    float rstd = rsqrtf(s2 / 256.f - mu * mu + LN_EPS);

    float p[6] = {0.f, 0.f, 0.f, 0.f, 0.f, 0.f};
    #pragma unroll
    for (int q = 0; q < 4; ++q) {
        int i = lane + 64 * q;
        float val = (z[q] - mu) * rstd * g[i] + bb[i];
        #pragma unroll
        for (int c = 0; c < 6; ++c)
            p[c] = fmaf(val, W_fc[i * 6 + c], p[c]);
    }
    #pragma unroll
    for (int c = 0; c < 6; ++c)
        #pragma unroll
        for (int off = 32; off > 0; off >>= 1) p[c] += __shfl_xor(p[c], off);

    if (lane < 6) {
        float o = p[0];
        o = (lane == 1) ? p[1] : o;
        o = (lane == 2) ? p[2] : o;
        o = (lane == 3) ? p[3] : o;
        o = (lane == 4) ? p[4] : o;
        o = (lane == 5) ? p[5] : o;
        out[(size_t)row * CDIM + lane] = o + b_fc[lane];
    }
}

extern "C" void kernel_launch(void* const* d_in, const int* in_sizes, int n_in,
                              void* d_out, int out_size, void* d_ws, size_t ws_size,
                              hipStream_t stream) {
    const float* x      = (const float*)d_in[0];
    const float* W_proj = (const float*)d_in[1];
    const float* b_proj = (const float*)d_in[2];
    const float* W_tau  = (const float*)d_in[3];
    const float* b_tau  = (const float*)d_in[4];
    const float* W_res  = (const float*)d_in[5];
    const float* b_res  = (const float*)d_in[6];
    const float* ln_g   = (const float*)d_in[7];
    const float* ln_b   = (const float*)d_in[8];
    const float* W_fc   = (const float*)d_in[9];
    const float* b_fc   = (const float*)d_in[10];
    float* out = (float*)d_out;

    char* ws = (char*)d_ws;
    float* sq   = (float*)ws;                        ws += (size_t)NROWS * 4;
    int*   kk   = (int*)ws;                          ws += (size_t)NROWS * 4;
    float* h    = (float*)ws;                        ws += (size_t)NROWS * HDIM * 4;
    float* r    = (float*)ws;                        ws += (size_t)NROWS * HDIM * 4;
    unsigned short* xb   = (unsigned short*)ws;      ws += (size_t)NROWS * DDIM * 2;
    unsigned short* aggb = (unsigned short*)ws;      ws += (size_t)NROWS * HDIM * 2;
    unsigned short* wpT  = (unsigned short*)ws;      ws += (size_t)DDIM * HDIM * 2;
    unsigned short* wrT  = (unsigned short*)ws;      ws += (size_t)HDIM * HDIM * 2;
    ws = (char*)(((size_t)ws + 255) & ~(size_t)255);
    unsigned int* keys = (unsigned int*)ws;          ws += (size_t)NROWS * 1024 * 4;   // 32 MB

    const int prepW = (DDIM * HDIM + HDIM * HDIM + 255) / 256;
    prep_kernel<<<NROWS / 4 + prepW, 256, 0, stream>>>(
        x, W_tau, b_tau, xb, sq, kk, W_proj, wpT, W_res, wrT);
    mfma_gemm_bias_relu_kernel<<<dim3(NROWS / 128, HDIM / 128), 256, 0, stream>>>(
        xb, wpT, b_proj, h, DDIM);
    dist_topk_kernel<<<(NROWS/128) * (NROWS/128 + 1) / 2, 256, 0, stream>>>(xb, sq, keys);
    topk_rescore_agg_kernel<<<NROWS / 4, 256, 0, stream>>>(keys, x, sq, kk, h, aggb);
    mfma_gemm_bias_relu_kernel<<<dim3(NROWS / 128, HDIM / 128), 256, 0, stream>>>(
        aggb, wrT, b_res, r, HDIM);
    ln_fc_kernel<<<NROWS / 4, 256, 0, stream>>>(h, r, ln_g, ln_b, W_fc, b_fc, out);
}

// Round 16
// 243.862 us; speedup vs baseline: 1.1995x; 1.0408x over previous
//
#include <hip/hip_runtime.h>
#include <hip/hip_fp16.h>
#include <math.h>

#define NROWS 8192
#define DDIM 384
#define HDIM 256
#define CDIM 6
#define LN_EPS 1e-5f
#define DSTR 138   // Dt row stride in halves (69 dwords, odd -> conflict-free scan)

typedef short bf16x8 __attribute__((ext_vector_type(8)));
typedef float f32x4 __attribute__((ext_vector_type(4)));
typedef unsigned short u16x8 __attribute__((ext_vector_type(8)));
typedef unsigned short u16x4 __attribute__((ext_vector_type(4)));
typedef unsigned short u16x2 __attribute__((ext_vector_type(2)));

__device__ __forceinline__ bool dj_better(float d1, int j1, float d2, int j2) {
    return (d1 < d2) || (d1 == d2 && j1 < j2);
}

__device__ __forceinline__ unsigned int umin_(unsigned int a, unsigned int b) { return a < b ? a : b; }
__device__ __forceinline__ unsigned int umax_(unsigned int a, unsigned int b) { return a > b ? a : b; }

// fp32 -> fp16 -> monotonic u16 (unsigned order == float order)
__device__ __forceinline__ unsigned short map16f(float v) {
    union { _Float16 f; unsigned short u; } c;
    c.f = (_Float16)v;
    unsigned short b = c.u;
    return (unsigned short)(b ^ (unsigned short)((((short)b) >> 15) | 0x8000));
}

__device__ __forceinline__ unsigned short rne_bf16(float v) {
    unsigned int u = __float_as_uint(v);
    u += 0x7fffu + ((u >> 16) & 1u);
    return (unsigned short)(u >> 16);
}

// branchless unsorted 8-slot top-8 insert (replace current max, recompute max)
__device__ __forceinline__ void ins8(
    unsigned int& s0, unsigned int& s1, unsigned int& s2, unsigned int& s3,
    unsigned int& s4, unsigned int& s5, unsigned int& s6, unsigned int& s7,
    unsigned int& m, unsigned int key)
{
    if (key < m) {
        s0 = (s0 == m) ? key : s0;
        s1 = (s1 == m) ? key : s1;
        s2 = (s2 == m) ? key : s2;
        s3 = (s3 == m) ? key : s3;
        s4 = (s4 == m) ? key : s4;
        s5 = (s5 == m) ? key : s5;
        s6 = (s6 == m) ? key : s6;
        s7 = (s7 == m) ? key : s7;
        m = umax_(umax_(umax_(s0, s1), umax_(s2, s3)),
                  umax_(umax_(s4, s5), umax_(s6, s7)));
    }
}

// ---------------- fused prep: xb/sq/kk (blocks 0..2047) + weight transposes ----------------
__global__ void __launch_bounds__(256) prep_kernel(
    const float* __restrict__ x, const float* __restrict__ W_tau,
    const float* __restrict__ b_tau, unsigned short* __restrict__ xb,
    float* __restrict__ sq, int* __restrict__ kk,
    const float* __restrict__ Wp, unsigned short* __restrict__ wpT,
    const float* __restrict__ Wr, unsigned short* __restrict__ wrT)
{
    int tid = threadIdx.x;
    if (blockIdx.x < NROWS / 4) {
        int wave = tid >> 6, lane = tid & 63;
        int row = blockIdx.x * 4 + wave;
        const float* xr = x + (size_t)row * DDIM;
        unsigned short* xbr = xb + (size_t)row * DDIM;
        float s = 0.f, tp = 0.f;
        #pragma unroll
        for (int q = 0; q < 6; ++q) {
            float v = xr[lane + 64 * q];
            xbr[lane + 64 * q] = rne_bf16(v);
            s = fmaf(v, v, s);
            tp = fmaf(v, W_tau[lane + 64 * q], tp);
        }
        #pragma unroll
        for (int off = 32; off > 0; off >>= 1) {
            s += __shfl_xor(s, off);
            tp += __shfl_xor(tp, off);
        }
        if (lane == 0) {
            sq[row] = s;
            float u = tp + b_tau[0];
            float tau = 1.f / (1.f + expf(-u));
            float kf = rintf(16.f - 12.f * tau);
            int k = (int)kf;
            k = min(16, max(1, k));
            kk[row] = k;
        }
    } else {
        int i = (blockIdx.x - NROWS / 4) * 256 + tid;
        if (i < DDIM * HDIM) {
            int k = i / HDIM, n = i % HDIM;
            wpT[(size_t)n * DDIM + k] = rne_bf16(Wp[i]);
        } else {
            int j = i - DDIM * HDIM;
            if (j < HDIM * HDIM) {
                int k = j / HDIM, n = j % HDIM;
                wrT[(size_t)n * HDIM + k] = rne_bf16(Wr[j]);
            }
        }
    }
}

// ---------------- MFMA bf16 GEMM: out = relu(A[M,K]@W + bias), W given as WT[n][k] ----------------
// Optionally also writes a bf16 copy of the output (hb) for cheap gathering.
__global__ void __launch_bounds__(256) mfma_gemm_bias_relu_kernel(
    const unsigned short* __restrict__ A, const unsigned short* __restrict__ WT,
    const float* __restrict__ bias, float* __restrict__ out,
    unsigned short* __restrict__ hb, int K)
{
    __shared__ unsigned short Abuf[128 * 32];
    __shared__ unsigned short Bbuf[128 * 32];

    const int tid = threadIdx.x;
    const int wave = tid >> 6;
    const int rowbase = blockIdx.x * 128;
    const int nbase = blockIdx.y * 128;
    const int lane = tid & 63;
    const int wr = (wave >> 1) * 64;
    const int wc = (wave & 1) * 64;
    const int m16 = lane & 15;
    const int kq = lane >> 4;

    const int er0 = tid >> 2;
    const int er1 = 64 + (tid >> 2);
    const int eko = tid & 3;

    f32x4 acc[4][4];
    #pragma unroll
    for (int a = 0; a < 4; ++a)
        #pragma unroll
        for (int b = 0; b < 4; ++b)
            acc[a][b] = (f32x4){0.f, 0.f, 0.f, 0.f};

    for (int kb = 0; kb < K / 32; ++kb) {
        const int k0 = kb * 32;
        __syncthreads();
        __builtin_amdgcn_global_load_lds(
            (const __attribute__((address_space(1))) void*)(A + (size_t)(rowbase + er0) * K + k0 + eko * 8),
            (__attribute__((address_space(3))) void*)((char*)Abuf + (wave * 64) * 16), 16, 0, 0);
        __builtin_amdgcn_global_load_lds(
            (const __attribute__((address_space(1))) void*)(A + (size_t)(rowbase + er1) * K + k0 + eko * 8),
            (__attribute__((address_space(3))) void*)((char*)Abuf + (256 + wave * 64) * 16), 16, 0, 0);
        __builtin_amdgcn_global_load_lds(
            (const __attribute__((address_space(1))) void*)(WT + (size_t)(nbase + er0) * K + k0 + eko * 8),
            (__attribute__((address_space(3))) void*)((char*)Bbuf + (wave * 64) * 16), 16, 0, 0);
        __builtin_amdgcn_global_load_lds(
            (const __attribute__((address_space(1))) void*)(WT + (size_t)(nbase + er1) * K + k0 + eko * 8),
            (__attribute__((address_space(3))) void*)((char*)Bbuf + (256 + wave * 64) * 16), 16, 0, 0);
        __syncthreads();

        bf16x8 af[4], bfr[4];
        #pragma unroll
        for (int s = 0; s < 4; ++s) {
            af[s]  = *(const bf16x8*)&Abuf[(wr + s * 16 + m16) * 32 + kq * 8];
            bfr[s] = *(const bf16x8*)&Bbuf[(wc + s * 16 + m16) * 32 + kq * 8];
        }
        #pragma unroll
        for (int si = 0; si < 4; ++si)
            #pragma unroll
            for (int sj = 0; sj < 4; ++sj)
                acc[si][sj] = __builtin_amdgcn_mfma_f32_16x16x32_bf16(
                    af[si], bfr[sj], acc[si][sj], 0, 0, 0);
    }

    #pragma unroll
    for (int sj = 0; sj < 4; ++sj) {
        int c = nbase + wc + sj * 16 + m16;
        float bc = bias[c];
        #pragma unroll
        for (int si = 0; si < 4; ++si) {
            int r = rowbase + wr + si * 16 + kq * 4;
            #pragma unroll
            for (int v = 0; v < 4; ++v) {
                float val = fmaxf(acc[si][sj][v] + bc, 0.f);
                out[(size_t)(r + v) * HDIM + c] = val;
                if (hb) hb[(size_t)(r + v) * HDIM + c] = rne_bf16(val);
            }
        }
    }
}

// ---------------- MFMA bf16 Gram GEMM + fused per-tile top-8 screening ----------------
__global__ void __launch_bounds__(256) dist_topk_kernel(
    const unsigned short* __restrict__ xb, const float* __restrict__ sq,
    unsigned int* __restrict__ keys)
{
    __shared__ unsigned short Abuf[128 * 32];                 // 8 KB
    __shared__ unsigned short Bbuf[128 * 32];                 // 8 KB
    __shared__ __align__(16) unsigned short Dt[128 * DSTR];   // 34.5 KB

    int t = blockIdx.x;
    int bi = (int)((sqrtf(8.f * (float)t + 1.f) - 1.f) * 0.5f);
    while ((bi + 1) * (bi + 2) / 2 <= t) ++bi;
    while (bi * (bi + 1) / 2 > t) --bi;
    int bj = t - bi * (bi + 1) / 2;

    const int tid = threadIdx.x;
    const int wave = tid >> 6;
    const int lane = tid & 63;
    const int rowbase = bi * 128;
    const int colbase = bj * 128;
    const int wr = (wave >> 1) * 64;
    const int wc = (wave & 1) * 64;
    const int m16 = lane & 15;
    const int kq = lane >> 4;

    const int er0 = tid >> 2;
    const int er1 = 64 + (tid >> 2);
    const int eko = tid & 3;

    f32x4 acc[4][4];
    #pragma unroll
    for (int a = 0; a < 4; ++a)
        #pragma unroll
        for (int b = 0; b < 4; ++b)
            acc[a][b] = (f32x4){0.f, 0.f, 0.f, 0.f};

    for (int kb = 0; kb < DDIM / 32; ++kb) {
        const int k0 = kb * 32;
        __syncthreads();
        __builtin_amdgcn_global_load_lds(
            (const __attribute__((address_space(1))) void*)(xb + (size_t)(rowbase + er0) * DDIM + k0 + eko * 8),
            (__attribute__((address_space(3))) void*)((char*)Abuf + (wave * 64) * 16), 16, 0, 0);
        __builtin_amdgcn_global_load_lds(
            (const __attribute__((address_space(1))) void*)(xb + (size_t)(rowbase + er1) * DDIM + k0 + eko * 8),
            (__attribute__((address_space(3))) void*)((char*)Abuf + (256 + wave * 64) * 16), 16, 0, 0);
        __builtin_amdgcn_global_load_lds(
            (const __attribute__((address_space(1))) void*)(xb + (size_t)(colbase + er0) * DDIM + k0 + eko * 8),
            (__attribute__((address_space(3))) void*)((char*)Bbuf + (wave * 64) * 16), 16, 0, 0);
        __builtin_amdgcn_global_load_lds(
            (const __attribute__((address_space(1))) void*)(xb + (size_t)(colbase + er1) * DDIM + k0 + eko * 8),
            (__attribute__((address_space(3))) void*)((char*)Bbuf + (256 + wave * 64) * 16), 16, 0, 0);
        __syncthreads();

        bf16x8 af[4], bfr[4];
        #pragma unroll
        for (int s = 0; s < 4; ++s) {
            af[s]  = *(const bf16x8*)&Abuf[(wr + s * 16 + m16) * 32 + kq * 8];
            bfr[s] = *(const bf16x8*)&Bbuf[(wc + s * 16 + m16) * 32 + kq * 8];
        }
        #pragma unroll
        for (int si = 0; si < 4; ++si)
            #pragma unroll
            for (int sj = 0; sj < 4; ++sj)
                acc[si][sj] = __builtin_amdgcn_mfma_f32_16x16x32_bf16(
                    af[si], bfr[sj], acc[si][sj], 0, 0, 0);
    }

    const int sr = tid >> 1;          // scan row in tile (0..127)
    const int seg = tid & 1;          // 64-col half

    // ==== pass 1: rows of bi-block ====
    {
        float sqc[4];
        #pragma unroll
        for (int sj = 0; sj < 4; ++sj) sqc[sj] = sq[colbase + wc + sj * 16 + m16];
        #pragma unroll
        for (int si = 0; si < 4; ++si)
            #pragma unroll
            for (int sj = 0; sj < 4; ++sj) {
                int r = wr + si * 16 + kq * 4;
                int c = wc + sj * 16 + m16;
                #pragma unroll
                for (int v = 0; v < 4; ++v)
                    Dt[(r + v) * DSTR + c] = map16f(sqc[sj] - 2.0f * acc[si][sj][v]);
            }
        __syncthreads();

        unsigned int s0 = 0xFFFFFFFFu, s1 = 0xFFFFFFFEu, s2 = 0xFFFFFFFDu, s3 = 0xFFFFFFFCu;
        unsigned int s4 = 0xFFFFFFFBu, s5 = 0xFFFFFFFAu, s6 = 0xFFFFFFF9u, s7 = 0xFFFFFFF8u;
        unsigned int m = 0xFFFFFFFFu;
        const unsigned short* rowp = &Dt[sr * DSTR + seg * 64];
        #pragma unroll
        for (int i = 0; i < 8; ++i) {
            u16x8 ch = *(const u16x8*)(rowp + i * 8);
            u16x4 g4 = __builtin_elementwise_min(
                __builtin_shufflevector(ch, ch, 0, 1, 2, 3),
                __builtin_shufflevector(ch, ch, 4, 5, 6, 7));
            u16x2 g2 = __builtin_elementwise_min(
                __builtin_shufflevector(g4, g4, 0, 1),
                __builtin_shufflevector(g4, g4, 2, 3));
            unsigned int gmin = umin_((unsigned int)g2[0], (unsigned int)g2[1]);
            if ((gmin << 13) < m) {
                int cb = colbase + seg * 64 + i * 8;
                #pragma unroll
                for (int e = 0; e < 8; ++e)
                    ins8(s0, s1, s2, s3, s4, s5, s6, s7, m,
                         ((unsigned int)ch[e] << 13) | (unsigned int)(cb + e));
            }
        }
        size_t kb = (size_t)(rowbase + sr) * 1024 + (size_t)bj * 16 + seg * 8;
        uint4 o0; o0.x = s0; o0.y = s1; o0.z = s2; o0.w = s3;
        uint4 o1; o1.x = s4; o1.y = s5; o1.z = s6; o1.w = s7;
        *(uint4*)&keys[kb] = o0;
        *(uint4*)&keys[kb + 4] = o1;
    }

    // ==== pass 2: rows of bj-block via transposed tile (off-diagonal only) ====
    if (bi != bj) {
        __syncthreads();
        #pragma unroll
        for (int si = 0; si < 4; ++si) {
            float4 sqr4 = *(const float4*)&sq[rowbase + wr + si * 16 + kq * 4];
            float srw[4] = {sqr4.x, sqr4.y, sqr4.z, sqr4.w};
            #pragma unroll
            for (int sj = 0; sj < 4; ++sj) {
                int r = wr + si * 16 + kq * 4;
                int c = wc + sj * 16 + m16;
                unsigned short h4[4];
                #pragma unroll
                for (int v = 0; v < 4; ++v)
                    h4[v] = map16f(srw[v] - 2.0f * acc[si][sj][v]);
                *(unsigned long long*)&Dt[c * DSTR + r] = *(unsigned long long*)h4;
            }
        }
        __syncthreads();

        unsigned int s0 = 0xFFFFFFFFu, s1 = 0xFFFFFFFEu, s2 = 0xFFFFFFFDu, s3 = 0xFFFFFFFCu;
        unsigned int s4 = 0xFFFFFFFBu, s5 = 0xFFFFFFFAu, s6 = 0xFFFFFFF9u, s7 = 0xFFFFFFF8u;
        unsigned int m = 0xFFFFFFFFu;
        const unsigned short* rowp = &Dt[sr * DSTR + seg * 64];
        #pragma unroll
        for (int i = 0; i < 8; ++i) {
            u16x8 ch = *(const u16x8*)(rowp + i * 8);
            u16x4 g4 = __builtin_elementwise_min(
                __builtin_shufflevector(ch, ch, 0, 1, 2, 3),
                __builtin_shufflevector(ch, ch, 4, 5, 6, 7));
            u16x2 g2 = __builtin_elementwise_min(
                __builtin_shufflevector(g4, g4, 0, 1),
                __builtin_shufflevector(g4, g4, 2, 3));
            unsigned int gmin = umin_((unsigned int)g2[0], (unsigned int)g2[1]);
            if ((gmin << 13) < m) {
                int cb = rowbase + seg * 64 + i * 8;
                #pragma unroll
                for (int e = 0; e < 8; ++e)
                    ins8(s0, s1, s2, s3, s4, s5, s6, s7, m,
                         ((unsigned int)ch[e] << 13) | (unsigned int)(cb + e));
            }
        }
        size_t kb = (size_t)(colbase + sr) * 1024 + (size_t)bi * 16 + seg * 8;
        uint4 o0; o0.x = s0; o0.y = s1; o0.z = s2; o0.w = s3;
        uint4 o1; o1.x = s4; o1.y = s5; o1.z = s6; o1.w = s7;
        *(uint4*)&keys[kb] = o0;
        *(uint4*)&keys[kb + 4] = o1;
    }
}

// ---------------- fused: merge keys -> top-32, split-wave exact rescore -> top-16, bf16 gather-mean ----------------
__global__ void __launch_bounds__(256) topk_rescore_agg_kernel(
    const unsigned int* __restrict__ keys, const float* __restrict__ x,
    const float* __restrict__ sq, const int* __restrict__ kk,
    const unsigned short* __restrict__ hb, unsigned short* __restrict__ aggb)
{
    const int w = threadIdx.x >> 6;
    const int row = blockIdx.x * 4 + w;
    const int lane = threadIdx.x & 63;
    __shared__ int sidx[4][16];

    // -- phase 1: merge 64x16 per-tile keys -> wave top-32 (unique integer keys) --
    const uint4* kp = (const uint4*)(keys + (size_t)row * 1024 + lane * 16);
    unsigned int s0 = 0xFFFFFFFFu, s1 = 0xFFFFFFFEu, s2 = 0xFFFFFFFDu, s3 = 0xFFFFFFFCu;
    unsigned int s4 = 0xFFFFFFFBu, s5 = 0xFFFFFFFAu, s6 = 0xFFFFFFF9u, s7 = 0xFFFFFFF8u;
    unsigned int m = 0xFFFFFFFFu;
    #pragma unroll
    for (int q = 0; q < 4; ++q) {
        uint4 v = kp[q];
        unsigned int gmin = umin_(umin_(v.x, v.y), umin_(v.z, v.w));
        if (gmin < m) {
            ins8(s0, s1, s2, s3, s4, s5, s6, s7, m, v.x);
            ins8(s0, s1, s2, s3, s4, s5, s6, s7, m, v.y);
            ins8(s0, s1, s2, s3, s4, s5, s6, s7, m, v.z);
            ins8(s0, s1, s2, s3, s4, s5, s6, s7, m, v.w);
        }
    }
    unsigned int lmin = umin_(umin_(umin_(s0, s1), umin_(s2, s3)),
                              umin_(umin_(s4, s5), umin_(s6, s7)));
    unsigned int myout = 0;
    for (int t = 0; t < 32; ++t) {
        unsigned int wv = lmin;
        #pragma unroll
        for (int off = 32; off > 0; off >>= 1)
            wv = umin_(wv, (unsigned int)__shfl_xor((int)wv, off));
        if (lane == t) myout = wv;
        if (lmin == wv) {
            s0 = (s0 == wv) ? 0xFFFFFFFFu : s0;
            s1 = (s1 == wv) ? 0xFFFFFFFFu : s1;
            s2 = (s2 == wv) ? 0xFFFFFFFFu : s2;
            s3 = (s3 == wv) ? 0xFFFFFFFFu : s3;
            s4 = (s4 == wv) ? 0xFFFFFFFFu : s4;
            s5 = (s5 == wv) ? 0xFFFFFFFFu : s5;
            s6 = (s6 == wv) ? 0xFFFFFFFFu : s6;
            s7 = (s7 == wv) ? 0xFFFFFFFFu : s7;
            lmin = umin_(umin_(umin_(s0, s1), umin_(s2, s3)),
                         umin_(umin_(s4, s5), umin_(s6, s7)));
        }
    }
    // candidate j for this lane (lanes 32-63 mirror 0-31)
    int myj = __shfl((int)(myout & 8191u), lane & 31);

    // -- phase 2: split-wave exact fp32 rescore (2 candidates per iteration) --
    const int l32 = lane & 31;
    const int half = lane >> 5;
    float xr[12];
    #pragma unroll
    for (int q = 0; q < 12; ++q) xr[q] = x[(size_t)row * DDIM + l32 + 32 * q];
    float sqrow = sq[row];
    float myd = 0.f;
    for (int i = 0; i < 16; ++i) {
        int c0 = 2 * i + half;                  // lower half: even cand, upper: odd
        int j = __shfl(myj, c0);
        const float* xc = x + (size_t)j * DDIM;
        float p = 0.f;
        #pragma unroll
        for (int q = 0; q < 12; ++q) p = fmaf(xr[q], xc[l32 + 32 * q], p);
        #pragma unroll
        for (int off = 16; off > 0; off >>= 1) p += __shfl_xor(p, off);   // stays within half
        float d = sqrow + sq[j] - 2.f * p;
        float d_even = __shfl(d, 0);            // candidate 2i  (lower half result)
        float d_odd  = __shfl(d, 32);           // candidate 2i+1 (upper half result)
        if (lane == 2 * i)     myd = d_even;
        if (lane == 2 * i + 1) myd = d_odd;
    }
    int rank = 0;
    for (int t = 0; t < 32; ++t) {
        float dt = __shfl(myd, t); int jt = __shfl(myj, t);
        if (dj_better(dt, jt, myd, myj)) ++rank;
    }
    if (lane < 32 && rank < 16) sidx[w][rank] = myj;
    __syncthreads();

    // -- phase 3: gather-mean of first k neighbors' bf16 h rows (1 dwordx2/lane/neighbor) --
    int k = kk[row];
    float a0 = 0.f, a1 = 0.f, a2 = 0.f, a3 = 0.f;
    for (int t = 0; t < k; ++t) {
        uint2 v = *(const uint2*)(hb + (size_t)sidx[w][t] * HDIM + lane * 4);
        a0 += __uint_as_float(v.x << 16);
        a1 += __uint_as_float(v.x & 0xFFFF0000u);
        a2 += __uint_as_float(v.y << 16);
        a3 += __uint_as_float(v.y & 0xFFFF0000u);
    }
    float inv = 1.f / (float)k;
    unsigned int b0 = rne_bf16(a0 * inv);
    unsigned int b1 = rne_bf16(a1 * inv);
    unsigned int b2 = rne_bf16(a2 * inv);
    unsigned int b3 = rne_bf16(a3 * inv);
    uint2 o; o.x = b0 | (b1 << 16); o.y = b2 | (b3 << 16);
    *(uint2*)(aggb + (size_t)row * HDIM + lane * 4) = o;
}

// ---------------- LayerNorm(h + r) * g + b, then @ W_fc + b_fc (one row per wave) ----------------
__global__ void __launch_bounds__(256) ln_fc_kernel(
    const float* __restrict__ h, const float* __restrict__ r,
    const float* __restrict__ g, const float* __restrict__ bb,
    const float* __restrict__ W_fc, const float* __restrict__ b_fc,
    float* __restrict__ out)
{
    const int row = blockIdx.x * 4 + (threadIdx.x >> 6);
    const int lane = threadIdx.x & 63;
    const float* hp = h + (size_t)row * HDIM;
    const float* rp = r + (size_t)row * HDIM;

    float z[4];
    #pragma unroll
    for (int q = 0; q < 4; ++q)
        z[q] = hp[lane + 64 * q] + rp[lane + 64 * q];

    float s = z[0] + z[1] + z[2] + z[3];
    float s2 = z[0]*z[0] + z[1]*z[1] + z[2]*z[2] + z[3]*z[3];
    #pragma unroll
    for (int off = 32; off > 0; off >>= 1) {
        s += __shfl_xor(s, off);
        s2 += __shfl_xor(s2, off);
    }
    float mu = s / 256.f;
    float rstd = rsqrtf(s2 / 256.f - mu * mu + LN_EPS);

    float p[6] = {0.f, 0.f, 0.f, 0.f, 0.f, 0.f};
    #pragma unroll
    for (int q = 0; q < 4; ++q) {
        int i = lane + 64 * q;
        float val = (z[q] - mu) * rstd * g[i] + bb[i];
        #pragma unroll
        for (int c = 0; c < 6; ++c)
            p[c] = fmaf(val, W_fc[i * 6 + c], p[c]);
    }
    #pragma unroll
    for (int c = 0; c < 6; ++c)
        #pragma unroll
        for (int off = 32; off > 0; off >>= 1) p[c] += __shfl_xor(p[c], off);

    if (lane < 6) {
        float o = p[0];
        o = (lane == 1) ? p[1] : o;
        o = (lane == 2) ? p[2] : o;
        o = (lane == 3) ? p[3] : o;
        o = (lane == 4) ? p[4] : o;
        o = (lane == 5) ? p[5] : o;
        out[(size_t)row * CDIM + lane] = o + b_fc[lane];
    }
}

extern "C" void kernel_launch(void* const* d_in, const int* in_sizes, int n_in,
                              void* d_out, int out_size, void* d_ws, size_t ws_size,
                              hipStream_t stream) {
    const float* x      = (const float*)d_in[0];
    const float* W_proj = (const float*)d_in[1];
    const float* b_proj = (const float*)d_in[2];
    const float* W_tau  = (const float*)d_in[3];
    const float* b_tau  = (const float*)d_in[4];
    const float* W_res  = (const float*)d_in[5];
    const float* b_res  = (const float*)d_in[6];
    const float* ln_g   = (const float*)d_in[7];
    const float* ln_b   = (const float*)d_in[8];
    const float* W_fc   = (const float*)d_in[9];
    const float* b_fc   = (const float*)d_in[10];
    float* out = (float*)d_out;

    char* ws = (char*)d_ws;
    float* sq   = (float*)ws;                        ws += (size_t)NROWS * 4;
    int*   kk   = (int*)ws;                          ws += (size_t)NROWS * 4;
    float* h    = (float*)ws;                        ws += (size_t)NROWS * HDIM * 4;
    float* r    = (float*)ws;                        ws += (size_t)NROWS * HDIM * 4;
    unsigned short* xb   = (unsigned short*)ws;      ws += (size_t)NROWS * DDIM * 2;
    unsigned short* hbuf = (unsigned short*)ws;      ws += (size_t)NROWS * HDIM * 2;
    unsigned short* aggb = (unsigned short*)ws;      ws += (size_t)NROWS * HDIM * 2;
    unsigned short* wpT  = (unsigned short*)ws;      ws += (size_t)DDIM * HDIM * 2;
    unsigned short* wrT  = (unsigned short*)ws;      ws += (size_t)HDIM * HDIM * 2;
    ws = (char*)(((size_t)ws + 255) & ~(size_t)255);
    unsigned int* keys = (unsigned int*)ws;          ws += (size_t)NROWS * 1024 * 4;   // 32 MB

    const int prepW = (DDIM * HDIM + HDIM * HDIM + 255) / 256;
    prep_kernel<<<NROWS / 4 + prepW, 256, 0, stream>>>(
        x, W_tau, b_tau, xb, sq, kk, W_proj, wpT, W_res, wrT);
    mfma_gemm_bias_relu_kernel<<<dim3(NROWS / 128, HDIM / 128), 256, 0, stream>>>(
        xb, wpT, b_proj, h, hbuf, DDIM);
    dist_topk_kernel<<<(NROWS/128) * (NROWS/128 + 1) / 2, 256, 0, stream>>>(xb, sq, keys);
    topk_rescore_agg_kernel<<<NROWS / 4, 256, 0, stream>>>(keys, x, sq, kk, hbuf, aggb);
    mfma_gemm_bias_relu_kernel<<<dim3(NROWS / 128, HDIM / 128), 256, 0, stream>>>(
        aggb, wrT, b_res, r, (unsigned short*)nullptr, HDIM);
    ln_fc_kernel<<<NROWS / 4, 256, 0, stream>>>(h, r, ln_g, ln_b, W_fc, b_fc, out);
}

// Round 17
// 239.094 us; speedup vs baseline: 1.2234x; 1.0199x over previous
//
#include <hip/hip_runtime.h>
#include <hip/hip_fp16.h>
#include <math.h>

#define NROWS 8192
#define DDIM 384
#define HDIM 256
#define CDIM 6
#define LN_EPS 1e-5f
#define DSTR 138   // Dt row stride in halves (69 dwords, odd -> conflict-free scan)

typedef short bf16x8 __attribute__((ext_vector_type(8)));
typedef float f32x4 __attribute__((ext_vector_type(4)));
typedef unsigned short u16x8 __attribute__((ext_vector_type(8)));
typedef unsigned short u16x4 __attribute__((ext_vector_type(4)));
typedef unsigned short u16x2 __attribute__((ext_vector_type(2)));

__device__ __forceinline__ bool dj_better(float d1, int j1, float d2, int j2) {
    return (d1 < d2) || (d1 == d2 && j1 < j2);
}

__device__ __forceinline__ unsigned int umin_(unsigned int a, unsigned int b) { return a < b ? a : b; }
__device__ __forceinline__ unsigned int umax_(unsigned int a, unsigned int b) { return a > b ? a : b; }

// fp32 -> fp16 -> monotonic u16 (unsigned order == float order)
__device__ __forceinline__ unsigned short map16f(float v) {
    union { _Float16 f; unsigned short u; } c;
    c.f = (_Float16)v;
    unsigned short b = c.u;
    return (unsigned short)(b ^ (unsigned short)((((short)b) >> 15) | 0x8000));
}

__device__ __forceinline__ unsigned short rne_bf16(float v) {
    unsigned int u = __float_as_uint(v);
    u += 0x7fffu + ((u >> 16) & 1u);
    return (unsigned short)(u >> 16);
}

// branchless unsorted 8-slot top-8 insert (replace current max, recompute max)
__device__ __forceinline__ void ins8(
    unsigned int& s0, unsigned int& s1, unsigned int& s2, unsigned int& s3,
    unsigned int& s4, unsigned int& s5, unsigned int& s6, unsigned int& s7,
    unsigned int& m, unsigned int key)
{
    if (key < m) {
        s0 = (s0 == m) ? key : s0;
        s1 = (s1 == m) ? key : s1;
        s2 = (s2 == m) ? key : s2;
        s3 = (s3 == m) ? key : s3;
        s4 = (s4 == m) ? key : s4;
        s5 = (s5 == m) ? key : s5;
        s6 = (s6 == m) ? key : s6;
        s7 = (s7 == m) ? key : s7;
        m = umax_(umax_(umax_(s0, s1), umax_(s2, s3)),
                  umax_(umax_(s4, s5), umax_(s6, s7)));
    }
}

__device__ __forceinline__ unsigned int max8_(
    unsigned int s0, unsigned int s1, unsigned int s2, unsigned int s3,
    unsigned int s4, unsigned int s5, unsigned int s6, unsigned int s7)
{
    return umax_(umax_(umax_(s0, s1), umax_(s2, s3)),
                 umax_(umax_(s4, s5), umax_(s6, s7)));
}

// ---------------- fused prep: xb/sq/kk (blocks 0..2047) + weight transposes ----------------
__global__ void __launch_bounds__(256) prep_kernel(
    const float* __restrict__ x, const float* __restrict__ W_tau,
    const float* __restrict__ b_tau, unsigned short* __restrict__ xb,
    float* __restrict__ sq, int* __restrict__ kk,
    const float* __restrict__ Wp, unsigned short* __restrict__ wpT,
    const float* __restrict__ Wr, unsigned short* __restrict__ wrT)
{
    int tid = threadIdx.x;
    if (blockIdx.x < NROWS / 4) {
        int wave = tid >> 6, lane = tid & 63;
        int row = blockIdx.x * 4 + wave;
        const float* xr = x + (size_t)row * DDIM;
        unsigned short* xbr = xb + (size_t)row * DDIM;
        float s = 0.f, tp = 0.f;
        #pragma unroll
        for (int q = 0; q < 6; ++q) {
            float v = xr[lane + 64 * q];
            xbr[lane + 64 * q] = rne_bf16(v);
            s = fmaf(v, v, s);
            tp = fmaf(v, W_tau[lane + 64 * q], tp);
        }
        #pragma unroll
        for (int off = 32; off > 0; off >>= 1) {
            s += __shfl_xor(s, off);
            tp += __shfl_xor(tp, off);
        }
        if (lane == 0) {
            sq[row] = s;
            float u = tp + b_tau[0];
            float tau = 1.f / (1.f + expf(-u));
            float kf = rintf(16.f - 12.f * tau);
            int k = (int)kf;
            k = min(16, max(1, k));
            kk[row] = k;
        }
    } else {
        int i = (blockIdx.x - NROWS / 4) * 256 + tid;
        if (i < DDIM * HDIM) {
            int k = i / HDIM, n = i % HDIM;
            wpT[(size_t)n * DDIM + k] = rne_bf16(Wp[i]);
        } else {
            int j = i - DDIM * HDIM;
            if (j < HDIM * HDIM) {
                int k = j / HDIM, n = j % HDIM;
                wrT[(size_t)n * HDIM + k] = rne_bf16(Wr[j]);
            }
        }
    }
}

// ---------------- MFMA bf16 GEMM: out = relu(A[M,K]@W + bias), W given as WT[n][k] ----------------
__global__ void __launch_bounds__(256) mfma_gemm_bias_relu_kernel(
    const unsigned short* __restrict__ A, const unsigned short* __restrict__ WT,
    const float* __restrict__ bias, float* __restrict__ out,
    unsigned short* __restrict__ hb, int K)
{
    __shared__ unsigned short Abuf[128 * 32];
    __shared__ unsigned short Bbuf[128 * 32];

    const int tid = threadIdx.x;
    const int wave = tid >> 6;
    const int rowbase = blockIdx.x * 128;
    const int nbase = blockIdx.y * 128;
    const int lane = tid & 63;
    const int wr = (wave >> 1) * 64;
    const int wc = (wave & 1) * 64;
    const int m16 = lane & 15;
    const int kq = lane >> 4;

    const int er0 = tid >> 2;
    const int er1 = 64 + (tid >> 2);
    const int eko = tid & 3;

    f32x4 acc[4][4];
    #pragma unroll
    for (int a = 0; a < 4; ++a)
        #pragma unroll
        for (int b = 0; b < 4; ++b)
            acc[a][b] = (f32x4){0.f, 0.f, 0.f, 0.f};

    for (int kb = 0; kb < K / 32; ++kb) {
        const int k0 = kb * 32;
        __syncthreads();
        __builtin_amdgcn_global_load_lds(
            (const __attribute__((address_space(1))) void*)(A + (size_t)(rowbase + er0) * K + k0 + eko * 8),
            (__attribute__((address_space(3))) void*)((char*)Abuf + (wave * 64) * 16), 16, 0, 0);
        __builtin_amdgcn_global_load_lds(
            (const __attribute__((address_space(1))) void*)(A + (size_t)(rowbase + er1) * K + k0 + eko * 8),
            (__attribute__((address_space(3))) void*)((char*)Abuf + (256 + wave * 64) * 16), 16, 0, 0);
        __builtin_amdgcn_global_load_lds(
            (const __attribute__((address_space(1))) void*)(WT + (size_t)(nbase + er0) * K + k0 + eko * 8),
            (__attribute__((address_space(3))) void*)((char*)Bbuf + (wave * 64) * 16), 16, 0, 0);
        __builtin_amdgcn_global_load_lds(
            (const __attribute__((address_space(1))) void*)(WT + (size_t)(nbase + er1) * K + k0 + eko * 8),
            (__attribute__((address_space(3))) void*)((char*)Bbuf + (256 + wave * 64) * 16), 16, 0, 0);
        __syncthreads();

        bf16x8 af[4], bfr[4];
        #pragma unroll
        for (int s = 0; s < 4; ++s) {
            af[s]  = *(const bf16x8*)&Abuf[(wr + s * 16 + m16) * 32 + kq * 8];
            bfr[s] = *(const bf16x8*)&Bbuf[(wc + s * 16 + m16) * 32 + kq * 8];
        }
        #pragma unroll
        for (int si = 0; si < 4; ++si)
            #pragma unroll
            for (int sj = 0; sj < 4; ++sj)
                acc[si][sj] = __builtin_amdgcn_mfma_f32_16x16x32_bf16(
                    af[si], bfr[sj], acc[si][sj], 0, 0, 0);
    }

    #pragma unroll
    for (int sj = 0; sj < 4; ++sj) {
        int c = nbase + wc + sj * 16 + m16;
        float bc = bias[c];
        #pragma unroll
        for (int si = 0; si < 4; ++si) {
            int r = rowbase + wr + si * 16 + kq * 4;
            #pragma unroll
            for (int v = 0; v < 4; ++v) {
                float val = fmaxf(acc[si][sj][v] + bc, 0.f);
                out[(size_t)(r + v) * HDIM + c] = val;
                if (hb) hb[(size_t)(r + v) * HDIM + c] = rne_bf16(val);
            }
        }
    }
}

// ---------------- MFMA bf16 Gram GEMM + fused per-tile top-8 screening ----------------
// Chunk-0 seeds the 8-slot list directly (no sentinel inserts).
__global__ void __launch_bounds__(256) dist_topk_kernel(
    const unsigned short* __restrict__ xb, const float* __restrict__ sq,
    unsigned int* __restrict__ keys)
{
    __shared__ unsigned short Abuf[128 * 32];                 // 8 KB
    __shared__ unsigned short Bbuf[128 * 32];                 // 8 KB
    __shared__ __align__(16) unsigned short Dt[128 * DSTR];   // 34.5 KB

    int t = blockIdx.x;
    int bi = (int)((sqrtf(8.f * (float)t + 1.f) - 1.f) * 0.5f);
    while ((bi + 1) * (bi + 2) / 2 <= t) ++bi;
    while (bi * (bi + 1) / 2 > t) --bi;
    int bj = t - bi * (bi + 1) / 2;

    const int tid = threadIdx.x;
    const int wave = tid >> 6;
    const int lane = tid & 63;
    const int rowbase = bi * 128;
    const int colbase = bj * 128;
    const int wr = (wave >> 1) * 64;
    const int wc = (wave & 1) * 64;
    const int m16 = lane & 15;
    const int kq = lane >> 4;

    const int er0 = tid >> 2;
    const int er1 = 64 + (tid >> 2);
    const int eko = tid & 3;

    f32x4 acc[4][4];
    #pragma unroll
    for (int a = 0; a < 4; ++a)
        #pragma unroll
        for (int b = 0; b < 4; ++b)
            acc[a][b] = (f32x4){0.f, 0.f, 0.f, 0.f};

    for (int kb = 0; kb < DDIM / 32; ++kb) {
        const int k0 = kb * 32;
        __syncthreads();
        __builtin_amdgcn_global_load_lds(
            (const __attribute__((address_space(1))) void*)(xb + (size_t)(rowbase + er0) * DDIM + k0 + eko * 8),
            (__attribute__((address_space(3))) void*)((char*)Abuf + (wave * 64) * 16), 16, 0, 0);
        __builtin_amdgcn_global_load_lds(
            (const __attribute__((address_space(1))) void*)(xb + (size_t)(rowbase + er1) * DDIM + k0 + eko * 8),
            (__attribute__((address_space(3))) void*)((char*)Abuf + (256 + wave * 64) * 16), 16, 0, 0);
        __builtin_amdgcn_global_load_lds(
            (const __attribute__((address_space(1))) void*)(xb + (size_t)(colbase + er0) * DDIM + k0 + eko * 8),
            (__attribute__((address_space(3))) void*)((char*)Bbuf + (wave * 64) * 16), 16, 0, 0);
        __builtin_amdgcn_global_load_lds(
            (const __attribute__((address_space(1))) void*)(xb + (size_t)(colbase + er1) * DDIM + k0 + eko * 8),
            (__attribute__((address_space(3))) void*)((char*)Bbuf + (256 + wave * 64) * 16), 16, 0, 0);
        __syncthreads();

        bf16x8 af[4], bfr[4];
        #pragma unroll
        for (int s = 0; s < 4; ++s) {
            af[s]  = *(const bf16x8*)&Abuf[(wr + s * 16 + m16) * 32 + kq * 8];
            bfr[s] = *(const bf16x8*)&Bbuf[(wc + s * 16 + m16) * 32 + kq * 8];
        }
        #pragma unroll
        for (int si = 0; si < 4; ++si)
            #pragma unroll
            for (int sj = 0; sj < 4; ++sj)
                acc[si][sj] = __builtin_amdgcn_mfma_f32_16x16x32_bf16(
                    af[si], bfr[sj], acc[si][sj], 0, 0, 0);
    }

    const int sr = tid >> 1;          // scan row in tile (0..127)
    const int seg = tid & 1;          // 64-col half

    // ==== pass 1: rows of bi-block ====
    {
        float sqc[4];
        #pragma unroll
        for (int sj = 0; sj < 4; ++sj) sqc[sj] = sq[colbase + wc + sj * 16 + m16];
        #pragma unroll
        for (int si = 0; si < 4; ++si)
            #pragma unroll
            for (int sj = 0; sj < 4; ++sj) {
                int r = wr + si * 16 + kq * 4;
                int c = wc + sj * 16 + m16;
                #pragma unroll
                for (int v = 0; v < 4; ++v)
                    Dt[(r + v) * DSTR + c] = map16f(sqc[sj] - 2.0f * acc[si][sj][v]);
            }
        __syncthreads();

        const unsigned short* rowp = &Dt[sr * DSTR + seg * 64];
        const int cb0 = colbase + seg * 64;
        // seed slots with chunk 0 (always the first 8 elements; unique keys)
        u16x8 c0 = *(const u16x8*)rowp;
        unsigned int s0 = ((unsigned int)c0[0] << 13) | (unsigned int)(cb0 + 0);
        unsigned int s1 = ((unsigned int)c0[1] << 13) | (unsigned int)(cb0 + 1);
        unsigned int s2 = ((unsigned int)c0[2] << 13) | (unsigned int)(cb0 + 2);
        unsigned int s3 = ((unsigned int)c0[3] << 13) | (unsigned int)(cb0 + 3);
        unsigned int s4 = ((unsigned int)c0[4] << 13) | (unsigned int)(cb0 + 4);
        unsigned int s5 = ((unsigned int)c0[5] << 13) | (unsigned int)(cb0 + 5);
        unsigned int s6 = ((unsigned int)c0[6] << 13) | (unsigned int)(cb0 + 6);
        unsigned int s7 = ((unsigned int)c0[7] << 13) | (unsigned int)(cb0 + 7);
        unsigned int m = max8_(s0, s1, s2, s3, s4, s5, s6, s7);
        #pragma unroll
        for (int i = 1; i < 8; ++i) {
            u16x8 ch = *(const u16x8*)(rowp + i * 8);
            u16x4 g4 = __builtin_elementwise_min(
                __builtin_shufflevector(ch, ch, 0, 1, 2, 3),
                __builtin_shufflevector(ch, ch, 4, 5, 6, 7));
            u16x2 g2 = __builtin_elementwise_min(
                __builtin_shufflevector(g4, g4, 0, 1),
                __builtin_shufflevector(g4, g4, 2, 3));
            unsigned int gmin = umin_((unsigned int)g2[0], (unsigned int)g2[1]);
            if ((gmin << 13) < m) {
                int cb = cb0 + i * 8;
                #pragma unroll
                for (int e = 0; e < 8; ++e)
                    ins8(s0, s1, s2, s3, s4, s5, s6, s7, m,
                         ((unsigned int)ch[e] << 13) | (unsigned int)(cb + e));
            }
        }
        size_t kb = (size_t)(rowbase + sr) * 1024 + (size_t)bj * 16 + seg * 8;
        uint4 o0; o0.x = s0; o0.y = s1; o0.z = s2; o0.w = s3;
        uint4 o1; o1.x = s4; o1.y = s5; o1.z = s6; o1.w = s7;
        *(uint4*)&keys[kb] = o0;
        *(uint4*)&keys[kb + 4] = o1;
    }

    // ==== pass 2: rows of bj-block via transposed tile (off-diagonal only) ====
    if (bi != bj) {
        __syncthreads();
        #pragma unroll
        for (int si = 0; si < 4; ++si) {
            float4 sqr4 = *(const float4*)&sq[rowbase + wr + si * 16 + kq * 4];
            float srw[4] = {sqr4.x, sqr4.y, sqr4.z, sqr4.w};
            #pragma unroll
            for (int sj = 0; sj < 4; ++sj) {
                int r = wr + si * 16 + kq * 4;
                int c = wc + sj * 16 + m16;
                unsigned short h4[4];
                #pragma unroll
                for (int v = 0; v < 4; ++v)
                    h4[v] = map16f(srw[v] - 2.0f * acc[si][sj][v]);
                *(unsigned long long*)&Dt[c * DSTR + r] = *(unsigned long long*)h4;
            }
        }
        __syncthreads();

        const unsigned short* rowp = &Dt[sr * DSTR + seg * 64];
        const int cb0 = rowbase + seg * 64;
        u16x8 c0 = *(const u16x8*)rowp;
        unsigned int s0 = ((unsigned int)c0[0] << 13) | (unsigned int)(cb0 + 0);
        unsigned int s1 = ((unsigned int)c0[1] << 13) | (unsigned int)(cb0 + 1);
        unsigned int s2 = ((unsigned int)c0[2] << 13) | (unsigned int)(cb0 + 2);
        unsigned int s3 = ((unsigned int)c0[3] << 13) | (unsigned int)(cb0 + 3);
        unsigned int s4 = ((unsigned int)c0[4] << 13) | (unsigned int)(cb0 + 4);
        unsigned int s5 = ((unsigned int)c0[5] << 13) | (unsigned int)(cb0 + 5);
        unsigned int s6 = ((unsigned int)c0[6] << 13) | (unsigned int)(cb0 + 6);
        unsigned int s7 = ((unsigned int)c0[7] << 13) | (unsigned int)(cb0 + 7);
        unsigned int m = max8_(s0, s1, s2, s3, s4, s5, s6, s7);
        #pragma unroll
        for (int i = 1; i < 8; ++i) {
            u16x8 ch = *(const u16x8*)(rowp + i * 8);
            u16x4 g4 = __builtin_elementwise_min(
                __builtin_shufflevector(ch, ch, 0, 1, 2, 3),
                __builtin_shufflevector(ch, ch, 4, 5, 6, 7));
            u16x2 g2 = __builtin_elementwise_min(
                __builtin_shufflevector(g4, g4, 0, 1),
                __builtin_shufflevector(g4, g4, 2, 3));
            unsigned int gmin = umin_((unsigned int)g2[0], (unsigned int)g2[1]);
            if ((gmin << 13) < m) {
                int cb = cb0 + i * 8;
                #pragma unroll
                for (int e = 0; e < 8; ++e)
                    ins8(s0, s1, s2, s3, s4, s5, s6, s7, m,
                         ((unsigned int)ch[e] << 13) | (unsigned int)(cb + e));
            }
        }
        size_t kb = (size_t)(colbase + sr) * 1024 + (size_t)bi * 16 + seg * 8;
        uint4 o0; o0.x = s0; o0.y = s1; o0.z = s2; o0.w = s3;
        uint4 o1; o1.x = s4; o1.y = s5; o1.z = s6; o1.w = s7;
        *(uint4*)&keys[kb] = o0;
        *(uint4*)&keys[kb + 4] = o1;
    }
}

// ---------------- fused: merge keys -> top-32, split-wave exact rescore -> top-16, bf16 gather-mean ----------------
__global__ void __launch_bounds__(256) topk_rescore_agg_kernel(
    const unsigned int* __restrict__ keys, const float* __restrict__ x,
    const float* __restrict__ sq, const int* __restrict__ kk,
    const unsigned short* __restrict__ hb, unsigned short* __restrict__ aggb)
{
    const int w = threadIdx.x >> 6;
    const int row = blockIdx.x * 4 + w;
    const int lane = threadIdx.x & 63;
    __shared__ int sidx[4][16];

    // -- phase 1: merge 64x16 per-tile keys -> wave top-32 (seed with first 8 keys) --
    const uint4* kp = (const uint4*)(keys + (size_t)row * 1024 + lane * 16);
    uint4 v0 = kp[0], v1 = kp[1];
    unsigned int s0 = v0.x, s1 = v0.y, s2 = v0.z, s3 = v0.w;
    unsigned int s4 = v1.x, s5 = v1.y, s6 = v1.z, s7 = v1.w;
    unsigned int m = max8_(s0, s1, s2, s3, s4, s5, s6, s7);
    #pragma unroll
    for (int q = 2; q < 4; ++q) {
        uint4 v = kp[q];
        unsigned int gmin = umin_(umin_(v.x, v.y), umin_(v.z, v.w));
        if (gmin < m) {
            ins8(s0, s1, s2, s3, s4, s5, s6, s7, m, v.x);
            ins8(s0, s1, s2, s3, s4, s5, s6, s7, m, v.y);
            ins8(s0, s1, s2, s3, s4, s5, s6, s7, m, v.z);
            ins8(s0, s1, s2, s3, s4, s5, s6, s7, m, v.w);
        }
    }
    unsigned int lmin = umin_(umin_(umin_(s0, s1), umin_(s2, s3)),
                              umin_(umin_(s4, s5), umin_(s6, s7)));
    unsigned int myout = 0;
    for (int t = 0; t < 32; ++t) {
        unsigned int wv = lmin;
        #pragma unroll
        for (int off = 32; off > 0; off >>= 1)
            wv = umin_(wv, (unsigned int)__shfl_xor((int)wv, off));
        if (lane == t) myout = wv;
        if (lmin == wv) {
            s0 = (s0 == wv) ? 0xFFFFFFFFu : s0;
            s1 = (s1 == wv) ? 0xFFFFFFFFu : s1;
            s2 = (s2 == wv) ? 0xFFFFFFFFu : s2;
            s3 = (s3 == wv) ? 0xFFFFFFFFu : s3;
            s4 = (s4 == wv) ? 0xFFFFFFFFu : s4;
            s5 = (s5 == wv) ? 0xFFFFFFFFu : s5;
            s6 = (s6 == wv) ? 0xFFFFFFFFu : s6;
            s7 = (s7 == wv) ? 0xFFFFFFFFu : s7;
            lmin = umin_(umin_(umin_(s0, s1), umin_(s2, s3)),
                         umin_(umin_(s4, s5), umin_(s6, s7)));
        }
    }
    // candidate j for this lane (lanes 32-63 mirror 0-31)
    int myj = __shfl((int)(myout & 8191u), lane & 31);

    // -- phase 2: split-wave exact fp32 rescore (2 candidates per iteration) --
    const int l32 = lane & 31;
    const int half = lane >> 5;
    float xr[12];
    #pragma unroll
    for (int q = 0; q < 12; ++q) xr[q] = x[(size_t)row * DDIM + l32 + 32 * q];
    float sqrow = sq[row];
    float myd = 0.f;
    for (int i = 0; i < 16; ++i) {
        int c0 = 2 * i + half;
        int j = __shfl(myj, c0);
        const float* xc = x + (size_t)j * DDIM;
        float p = 0.f;
        #pragma unroll
        for (int q = 0; q < 12; ++q) p = fmaf(xr[q], xc[l32 + 32 * q], p);
        #pragma unroll
        for (int off = 16; off > 0; off >>= 1) p += __shfl_xor(p, off);
        float d = sqrow + sq[j] - 2.f * p;
        float d_even = __shfl(d, 0);
        float d_odd  = __shfl(d, 32);
        if (lane == 2 * i)     myd = d_even;
        if (lane == 2 * i + 1) myd = d_odd;
    }
    int rank = 0;
    for (int t = 0; t < 32; ++t) {
        float dt = __shfl(myd, t); int jt = __shfl(myj, t);
        if (dj_better(dt, jt, myd, myj)) ++rank;
    }
    if (lane < 32 && rank < 16) sidx[w][rank] = myj;
    __syncthreads();

    // -- phase 3: gather-mean of first k neighbors' bf16 h rows --
    int k = kk[row];
    float a0 = 0.f, a1 = 0.f, a2 = 0.f, a3 = 0.f;
    for (int t = 0; t < k; ++t) {
        uint2 v = *(const uint2*)(hb + (size_t)sidx[w][t] * HDIM + lane * 4);
        a0 += __uint_as_float(v.x << 16);
        a1 += __uint_as_float(v.x & 0xFFFF0000u);
        a2 += __uint_as_float(v.y << 16);
        a3 += __uint_as_float(v.y & 0xFFFF0000u);
    }
    float inv = 1.f / (float)k;
    unsigned int b0 = rne_bf16(a0 * inv);
    unsigned int b1 = rne_bf16(a1 * inv);
    unsigned int b2 = rne_bf16(a2 * inv);
    unsigned int b3 = rne_bf16(a3 * inv);
    uint2 o; o.x = b0 | (b1 << 16); o.y = b2 | (b3 << 16);
    *(uint2*)(aggb + (size_t)row * HDIM + lane * 4) = o;
}

// ---------------- LayerNorm(h + r) * g + b, then @ W_fc + b_fc (one row per wave) ----------------
__global__ void __launch_bounds__(256) ln_fc_kernel(
    const float* __restrict__ h, const float* __restrict__ r,
    const float* __restrict__ g, const float* __restrict__ bb,
    const float* __restrict__ W_fc, const float* __restrict__ b_fc,
    float* __restrict__ out)
{
    const int row = blockIdx.x * 4 + (threadIdx.x >> 6);
    const int lane = threadIdx.x & 63;
    const float* hp = h + (size_t)row * HDIM;
    const float* rp = r + (size_t)row * HDIM;

    float z[4];
    #pragma unroll
    for (int q = 0; q < 4; ++q)
        z[q] = hp[lane + 64 * q] + rp[lane + 64 * q];

    float s = z[0] + z[1] + z[2] + z[3];
    float s2 = z[0]*z[0] + z[1]*z[1] + z[2]*z[2] + z[3]*z[3];
    #pragma unroll
    for (int off = 32; off > 0; off >>= 1) {
        s += __shfl_xor(s, off);
        s2 += __shfl_xor(s2, off);
    }
    float mu = s / 256.f;
    float rstd = rsqrtf(s2 / 256.f - mu * mu + LN_EPS);

    float p[6] = {0.f, 0.f, 0.f, 0.f, 0.f, 0.f};
    #pragma unroll
    for (int q = 0; q < 4; ++q) {
        int i = lane + 64 * q;
        float val = (z[q] - mu) * rstd * g[i] + bb[i];
        #pragma unroll
        for (int c = 0; c < 6; ++c)
            p[c] = fmaf(val, W_fc[i * 6 + c], p[c]);
    }
    #pragma unroll
    for (int c = 0; c < 6; ++c)
        #pragma unroll
        for (int off = 32; off > 0; off >>= 1) p[c] += __shfl_xor(p[c], off);

    if (lane < 6) {
        float o = p[0];
        o = (lane == 1) ? p[1] : o;
        o = (lane == 2) ? p[2] : o;
        o = (lane == 3) ? p[3] : o;
        o = (lane == 4) ? p[4] : o;
        o = (lane == 5) ? p[5] : o;
        out[(size_t)row * CDIM + lane] = o + b_fc[lane];
    }
}

extern "C" void kernel_launch(void* const* d_in, const int* in_sizes, int n_in,
                              void* d_out, int out_size, void* d_ws, size_t ws_size,
                              hipStream_t stream) {
    const float* x      = (const float*)d_in[0];
    const float* W_proj = (const float*)d_in[1];
    const float* b_proj = (const float*)d_in[2];
    const float* W_tau  = (const float*)d_in[3];
    const float* b_tau  = (const float*)d_in[4];
    const float* W_res  = (const float*)d_in[5];
    const float* b_res  = (const float*)d_in[6];
    const float* ln_g   = (const float*)d_in[7];
    const float* ln_b   = (const float*)d_in[8];
    const float* W_fc   = (const float*)d_in[9];
    const float* b_fc   = (const float*)d_in[10];
    float* out = (float*)d_out;

    char* ws = (char*)d_ws;
    float* sq   = (float*)ws;                        ws += (size_t)NROWS * 4;
    int*   kk   = (int*)ws;                          ws += (size_t)NROWS * 4;
    float* h    = (float*)ws;                        ws += (size_t)NROWS * HDIM * 4;
    float* r    = (float*)ws;                        ws += (size_t)NROWS * HDIM * 4;
    unsigned short* xb   = (unsigned short*)ws;      ws += (size_t)NROWS * DDIM * 2;
    unsigned short* hbuf = (unsigned short*)ws;      ws += (size_t)NROWS * HDIM * 2;
    unsigned short* aggb = (unsigned short*)ws;      ws += (size_t)NROWS * HDIM * 2;
    unsigned short* wpT  = (unsigned short*)ws;      ws += (size_t)DDIM * HDIM * 2;
    unsigned short* wrT  = (unsigned short*)ws;      ws += (size_t)HDIM * HDIM * 2;
    ws = (char*)(((size_t)ws + 255) & ~(size_t)255);
    unsigned int* keys = (unsigned int*)ws;          ws += (size_t)NROWS * 1024 * 4;   // 32 MB

    const int prepW = (DDIM * HDIM + HDIM * HDIM + 255) / 256;
    prep_kernel<<<NROWS / 4 + prepW, 256, 0, stream>>>(
        x, W_tau, b_tau, xb, sq, kk, W_proj, wpT, W_res, wrT);
    mfma_gemm_bias_relu_kernel<<<dim3(NROWS / 128, HDIM / 128), 256, 0, stream>>>(
        xb, wpT, b_proj, h, hbuf, DDIM);
    dist_topk_kernel<<<(NROWS/128) * (NROWS/128 + 1) / 2, 256, 0, stream>>>(xb, sq, keys);
    topk_rescore_agg_kernel<<<NROWS / 4, 256, 0, stream>>>(keys, x, sq, kk, hbuf, aggb);
    mfma_gemm_bias_relu_kernel<<<dim3(NROWS / 128, HDIM / 128), 256, 0, stream>>>(
        aggb, wrT, b_res, r, (unsigned short*)nullptr, HDIM);
    ln_fc_kernel<<<NROWS / 4, 256, 0, stream>>>(h, r, ln_g, ln_b, W_fc, b_fc, out);
}

// Round 18
// 229.200 us; speedup vs baseline: 1.2762x; 1.0432x over previous
//
#include <hip/hip_runtime.h>
#include <hip/hip_fp16.h>
#include <math.h>

#define NROWS 8192
#define DDIM 384
#define HDIM 256
#define CDIM 6
#define LN_EPS 1e-5f
#define DSTR 138   // Dt row stride in halves (69 dwords, odd -> conflict-free scan)

typedef short bf16x8 __attribute__((ext_vector_type(8)));
typedef float f32x4 __attribute__((ext_vector_type(4)));
typedef unsigned short u16x8 __attribute__((ext_vector_type(8)));
typedef unsigned short u16x4 __attribute__((ext_vector_type(4)));
typedef unsigned short u16x2 __attribute__((ext_vector_type(2)));

__device__ __forceinline__ bool dj_better(float d1, int j1, float d2, int j2) {
    return (d1 < d2) || (d1 == d2 && j1 < j2);
}

__device__ __forceinline__ unsigned int umin_(unsigned int a, unsigned int b) { return a < b ? a : b; }
__device__ __forceinline__ unsigned int umax_(unsigned int a, unsigned int b) { return a > b ? a : b; }

// fp32 -> fp16 -> monotonic u16 (unsigned order == float order)
__device__ __forceinline__ unsigned short map16f(float v) {
    union { _Float16 f; unsigned short u; } c;
    c.f = (_Float16)v;
    unsigned short b = c.u;
    return (unsigned short)(b ^ (unsigned short)((((short)b) >> 15) | 0x8000));
}

// inverse of map16f: monotonic u16 -> fp16 bits -> float
__device__ __forceinline__ float unmap16(unsigned int m16b) {
    unsigned short fb = (m16b & 0x8000u) ? (unsigned short)(m16b ^ 0x8000u)
                                         : (unsigned short)(~m16b);
    union { unsigned short u; _Float16 f; } cv; cv.u = fb;
    return (float)cv.f;
}

__device__ __forceinline__ unsigned short rne_bf16(float v) {
    unsigned int u = __float_as_uint(v);
    u += 0x7fffu + ((u >> 16) & 1u);
    return (unsigned short)(u >> 16);
}

// branchless unsorted 8-slot top-8 insert (replace current max, recompute max)
__device__ __forceinline__ void ins8(
    unsigned int& s0, unsigned int& s1, unsigned int& s2, unsigned int& s3,
    unsigned int& s4, unsigned int& s5, unsigned int& s6, unsigned int& s7,
    unsigned int& m, unsigned int key)
{
    if (key < m) {
        s0 = (s0 == m) ? key : s0;
        s1 = (s1 == m) ? key : s1;
        s2 = (s2 == m) ? key : s2;
        s3 = (s3 == m) ? key : s3;
        s4 = (s4 == m) ? key : s4;
        s5 = (s5 == m) ? key : s5;
        s6 = (s6 == m) ? key : s6;
        s7 = (s7 == m) ? key : s7;
        m = umax_(umax_(umax_(s0, s1), umax_(s2, s3)),
                  umax_(umax_(s4, s5), umax_(s6, s7)));
    }
}

__device__ __forceinline__ unsigned int max8_(
    unsigned int s0, unsigned int s1, unsigned int s2, unsigned int s3,
    unsigned int s4, unsigned int s5, unsigned int s6, unsigned int s7)
{
    return umax_(umax_(umax_(s0, s1), umax_(s2, s3)),
                 umax_(umax_(s4, s5), umax_(s6, s7)));
}

// ---------------- fused prep: xb/sq/kk (blocks 0..2047) + weight transposes ----------------
__global__ void __launch_bounds__(256) prep_kernel(
    const float* __restrict__ x, const float* __restrict__ W_tau,
    const float* __restrict__ b_tau, unsigned short* __restrict__ xb,
    float* __restrict__ sq, int* __restrict__ kk,
    const float* __restrict__ Wp, unsigned short* __restrict__ wpT,
    const float* __restrict__ Wr, unsigned short* __restrict__ wrT)
{
    int tid = threadIdx.x;
    if (blockIdx.x < NROWS / 4) {
        int wave = tid >> 6, lane = tid & 63;
        int row = blockIdx.x * 4 + wave;
        const float* xr = x + (size_t)row * DDIM;
        unsigned short* xbr = xb + (size_t)row * DDIM;
        float s = 0.f, tp = 0.f;
        #pragma unroll
        for (int q = 0; q < 6; ++q) {
            float v = xr[lane + 64 * q];
            xbr[lane + 64 * q] = rne_bf16(v);
            s = fmaf(v, v, s);
            tp = fmaf(v, W_tau[lane + 64 * q], tp);
        }
        #pragma unroll
        for (int off = 32; off > 0; off >>= 1) {
            s += __shfl_xor(s, off);
            tp += __shfl_xor(tp, off);
        }
        if (lane == 0) {
            sq[row] = s;
            float u = tp + b_tau[0];
            float tau = 1.f / (1.f + expf(-u));
            float kf = rintf(16.f - 12.f * tau);
            int k = (int)kf;
            k = min(16, max(1, k));
            kk[row] = k;
        }
    } else {
        int i = (blockIdx.x - NROWS / 4) * 256 + tid;
        if (i < DDIM * HDIM) {
            int k = i / HDIM, n = i % HDIM;
            wpT[(size_t)n * DDIM + k] = rne_bf16(Wp[i]);
        } else {
            int j = i - DDIM * HDIM;
            if (j < HDIM * HDIM) {
                int k = j / HDIM, n = j % HDIM;
                wrT[(size_t)n * HDIM + k] = rne_bf16(Wr[j]);
            }
        }
    }
}

// ---------------- MFMA bf16 GEMM: out = relu(A[M,K]@W + bias), W given as WT[n][k] ----------------
__global__ void __launch_bounds__(256) mfma_gemm_bias_relu_kernel(
    const unsigned short* __restrict__ A, const unsigned short* __restrict__ WT,
    const float* __restrict__ bias, float* __restrict__ out,
    unsigned short* __restrict__ hb, int K)
{
    __shared__ unsigned short Abuf[128 * 32];
    __shared__ unsigned short Bbuf[128 * 32];

    const int tid = threadIdx.x;
    const int wave = tid >> 6;
    const int rowbase = blockIdx.x * 128;
    const int nbase = blockIdx.y * 128;
    const int lane = tid & 63;
    const int wr = (wave >> 1) * 64;
    const int wc = (wave & 1) * 64;
    const int m16 = lane & 15;
    const int kq = lane >> 4;

    const int er0 = tid >> 2;
    const int er1 = 64 + (tid >> 2);
    const int eko = tid & 3;

    f32x4 acc[4][4];
    #pragma unroll
    for (int a = 0; a < 4; ++a)
        #pragma unroll
        for (int b = 0; b < 4; ++b)
            acc[a][b] = (f32x4){0.f, 0.f, 0.f, 0.f};

    for (int kb = 0; kb < K / 32; ++kb) {
        const int k0 = kb * 32;
        __syncthreads();
        __builtin_amdgcn_global_load_lds(
            (const __attribute__((address_space(1))) void*)(A + (size_t)(rowbase + er0) * K + k0 + eko * 8),
            (__attribute__((address_space(3))) void*)((char*)Abuf + (wave * 64) * 16), 16, 0, 0);
        __builtin_amdgcn_global_load_lds(
            (const __attribute__((address_space(1))) void*)(A + (size_t)(rowbase + er1) * K + k0 + eko * 8),
            (__attribute__((address_space(3))) void*)((char*)Abuf + (256 + wave * 64) * 16), 16, 0, 0);
        __builtin_amdgcn_global_load_lds(
            (const __attribute__((address_space(1))) void*)(WT + (size_t)(nbase + er0) * K + k0 + eko * 8),
            (__attribute__((address_space(3))) void*)((char*)Bbuf + (wave * 64) * 16), 16, 0, 0);
        __builtin_amdgcn_global_load_lds(
            (const __attribute__((address_space(1))) void*)(WT + (size_t)(nbase + er1) * K + k0 + eko * 8),
            (__attribute__((address_space(3))) void*)((char*)Bbuf + (256 + wave * 64) * 16), 16, 0, 0);
        __syncthreads();

        bf16x8 af[4], bfr[4];
        #pragma unroll
        for (int s = 0; s < 4; ++s) {
            af[s]  = *(const bf16x8*)&Abuf[(wr + s * 16 + m16) * 32 + kq * 8];
            bfr[s] = *(const bf16x8*)&Bbuf[(wc + s * 16 + m16) * 32 + kq * 8];
        }
        #pragma unroll
        for (int si = 0; si < 4; ++si)
            #pragma unroll
            for (int sj = 0; sj < 4; ++sj)
                acc[si][sj] = __builtin_amdgcn_mfma_f32_16x16x32_bf16(
                    af[si], bfr[sj], acc[si][sj], 0, 0, 0);
    }

    #pragma unroll
    for (int sj = 0; sj < 4; ++sj) {
        int c = nbase + wc + sj * 16 + m16;
        float bc = bias[c];
        #pragma unroll
        for (int si = 0; si < 4; ++si) {
            int r = rowbase + wr + si * 16 + kq * 4;
            #pragma unroll
            for (int v = 0; v < 4; ++v) {
                float val = fmaxf(acc[si][sj][v] + bc, 0.f);
                out[(size_t)(r + v) * HDIM + c] = val;
                if (hb) hb[(size_t)(r + v) * HDIM + c] = rne_bf16(val);
            }
        }
    }
}

// ---------------- MFMA bf16 Gram GEMM + fused per-tile top-8 screening ----------------
__global__ void __launch_bounds__(256) dist_topk_kernel(
    const unsigned short* __restrict__ xb, const float* __restrict__ sq,
    unsigned int* __restrict__ keys)
{
    __shared__ unsigned short Abuf[128 * 32];                 // 8 KB
    __shared__ unsigned short Bbuf[128 * 32];                 // 8 KB
    __shared__ __align__(16) unsigned short Dt[128 * DSTR];   // 34.5 KB

    int t = blockIdx.x;
    int bi = (int)((sqrtf(8.f * (float)t + 1.f) - 1.f) * 0.5f);
    while ((bi + 1) * (bi + 2) / 2 <= t) ++bi;
    while (bi * (bi + 1) / 2 > t) --bi;
    int bj = t - bi * (bi + 1) / 2;

    const int tid = threadIdx.x;
    const int wave = tid >> 6;
    const int lane = tid & 63;
    const int rowbase = bi * 128;
    const int colbase = bj * 128;
    const int wr = (wave >> 1) * 64;
    const int wc = (wave & 1) * 64;
    const int m16 = lane & 15;
    const int kq = lane >> 4;

    const int er0 = tid >> 2;
    const int er1 = 64 + (tid >> 2);
    const int eko = tid & 3;

    f32x4 acc[4][4];
    #pragma unroll
    for (int a = 0; a < 4; ++a)
        #pragma unroll
        for (int b = 0; b < 4; ++b)
            acc[a][b] = (f32x4){0.f, 0.f, 0.f, 0.f};

    for (int kb = 0; kb < DDIM / 32; ++kb) {
        const int k0 = kb * 32;
        __syncthreads();
        __builtin_amdgcn_global_load_lds(
            (const __attribute__((address_space(1))) void*)(xb + (size_t)(rowbase + er0) * DDIM + k0 + eko * 8),
            (__attribute__((address_space(3))) void*)((char*)Abuf + (wave * 64) * 16), 16, 0, 0);
        __builtin_amdgcn_global_load_lds(
            (const __attribute__((address_space(1))) void*)(xb + (size_t)(rowbase + er1) * DDIM + k0 + eko * 8),
            (__attribute__((address_space(3))) void*)((char*)Abuf + (256 + wave * 64) * 16), 16, 0, 0);
        __builtin_amdgcn_global_load_lds(
            (const __attribute__((address_space(1))) void*)(xb + (size_t)(colbase + er0) * DDIM + k0 + eko * 8),
            (__attribute__((address_space(3))) void*)((char*)Bbuf + (wave * 64) * 16), 16, 0, 0);
        __builtin_amdgcn_global_load_lds(
            (const __attribute__((address_space(1))) void*)(xb + (size_t)(colbase + er1) * DDIM + k0 + eko * 8),
            (__attribute__((address_space(3))) void*)((char*)Bbuf + (256 + wave * 64) * 16), 16, 0, 0);
        __syncthreads();

        bf16x8 af[4], bfr[4];
        #pragma unroll
        for (int s = 0; s < 4; ++s) {
            af[s]  = *(const bf16x8*)&Abuf[(wr + s * 16 + m16) * 32 + kq * 8];
            bfr[s] = *(const bf16x8*)&Bbuf[(wc + s * 16 + m16) * 32 + kq * 8];
        }
        #pragma unroll
        for (int si = 0; si < 4; ++si)
            #pragma unroll
            for (int sj = 0; sj < 4; ++sj)
                acc[si][sj] = __builtin_amdgcn_mfma_f32_16x16x32_bf16(
                    af[si], bfr[sj], acc[si][sj], 0, 0, 0);
    }

    const int sr = tid >> 1;          // scan row in tile (0..127)
    const int seg = tid & 1;          // 64-col half

    // ==== pass 1: rows of bi-block ====
    {
        float sqc[4];
        #pragma unroll
        for (int sj = 0; sj < 4; ++sj) sqc[sj] = sq[colbase + wc + sj * 16 + m16];
        #pragma unroll
        for (int si = 0; si < 4; ++si)
            #pragma unroll
            for (int sj = 0; sj < 4; ++sj) {
                int r = wr + si * 16 + kq * 4;
                int c = wc + sj * 16 + m16;
                #pragma unroll
                for (int v = 0; v < 4; ++v)
                    Dt[(r + v) * DSTR + c] = map16f(sqc[sj] - 2.0f * acc[si][sj][v]);
            }
        __syncthreads();

        const unsigned short* rowp = &Dt[sr * DSTR + seg * 64];
        const int cb0 = colbase + seg * 64;
        u16x8 c0 = *(const u16x8*)rowp;
        unsigned int s0 = ((unsigned int)c0[0] << 13) | (unsigned int)(cb0 + 0);
        unsigned int s1 = ((unsigned int)c0[1] << 13) | (unsigned int)(cb0 + 1);
        unsigned int s2 = ((unsigned int)c0[2] << 13) | (unsigned int)(cb0 + 2);
        unsigned int s3 = ((unsigned int)c0[3] << 13) | (unsigned int)(cb0 + 3);
        unsigned int s4 = ((unsigned int)c0[4] << 13) | (unsigned int)(cb0 + 4);
        unsigned int s5 = ((unsigned int)c0[5] << 13) | (unsigned int)(cb0 + 5);
        unsigned int s6 = ((unsigned int)c0[6] << 13) | (unsigned int)(cb0 + 6);
        unsigned int s7 = ((unsigned int)c0[7] << 13) | (unsigned int)(cb0 + 7);
        unsigned int m = max8_(s0, s1, s2, s3, s4, s5, s6, s7);
        #pragma unroll
        for (int i = 1; i < 8; ++i) {
            u16x8 ch = *(const u16x8*)(rowp + i * 8);
            u16x4 g4 = __builtin_elementwise_min(
                __builtin_shufflevector(ch, ch, 0, 1, 2, 3),
                __builtin_shufflevector(ch, ch, 4, 5, 6, 7));
            u16x2 g2 = __builtin_elementwise_min(
                __builtin_shufflevector(g4, g4, 0, 1),
                __builtin_shufflevector(g4, g4, 2, 3));
            unsigned int gmin = umin_((unsigned int)g2[0], (unsigned int)g2[1]);
            if ((gmin << 13) < m) {
                int cb = cb0 + i * 8;
                #pragma unroll
                for (int e = 0; e < 8; ++e)
                    ins8(s0, s1, s2, s3, s4, s5, s6, s7, m,
                         ((unsigned int)ch[e] << 13) | (unsigned int)(cb + e));
            }
        }
        size_t kb = (size_t)(rowbase + sr) * 1024 + (size_t)bj * 16 + seg * 8;
        uint4 o0; o0.x = s0; o0.y = s1; o0.z = s2; o0.w = s3;
        uint4 o1; o1.x = s4; o1.y = s5; o1.z = s6; o1.w = s7;
        *(uint4*)&keys[kb] = o0;
        *(uint4*)&keys[kb + 4] = o1;
    }

    // ==== pass 2: rows of bj-block via transposed tile (off-diagonal only) ====
    if (bi != bj) {
        __syncthreads();
        #pragma unroll
        for (int si = 0; si < 4; ++si) {
            float4 sqr4 = *(const float4*)&sq[rowbase + wr + si * 16 + kq * 4];
            float srw[4] = {sqr4.x, sqr4.y, sqr4.z, sqr4.w};
            #pragma unroll
            for (int sj = 0; sj < 4; ++sj) {
                int r = wr + si * 16 + kq * 4;
                int c = wc + sj * 16 + m16;
                unsigned short h4[4];
                #pragma unroll
                for (int v = 0; v < 4; ++v)
                    h4[v] = map16f(srw[v] - 2.0f * acc[si][sj][v]);
                *(unsigned long long*)&Dt[c * DSTR + r] = *(unsigned long long*)h4;
            }
        }
        __syncthreads();

        const unsigned short* rowp = &Dt[sr * DSTR + seg * 64];
        const int cb0 = rowbase + seg * 64;
        u16x8 c0 = *(const u16x8*)rowp;
        unsigned int s0 = ((unsigned int)c0[0] << 13) | (unsigned int)(cb0 + 0);
        unsigned int s1 = ((unsigned int)c0[1] << 13) | (unsigned int)(cb0 + 1);
        unsigned int s2 = ((unsigned int)c0[2] << 13) | (unsigned int)(cb0 + 2);
        unsigned int s3 = ((unsigned int)c0[3] << 13) | (unsigned int)(cb0 + 3);
        unsigned int s4 = ((unsigned int)c0[4] << 13) | (unsigned int)(cb0 + 4);
        unsigned int s5 = ((unsigned int)c0[5] << 13) | (unsigned int)(cb0 + 5);
        unsigned int s6 = ((unsigned int)c0[6] << 13) | (unsigned int)(cb0 + 6);
        unsigned int s7 = ((unsigned int)c0[7] << 13) | (unsigned int)(cb0 + 7);
        unsigned int m = max8_(s0, s1, s2, s3, s4, s5, s6, s7);
        #pragma unroll
        for (int i = 1; i < 8; ++i) {
            u16x8 ch = *(const u16x8*)(rowp + i * 8);
            u16x4 g4 = __builtin_elementwise_min(
                __builtin_shufflevector(ch, ch, 0, 1, 2, 3),
                __builtin_shufflevector(ch, ch, 4, 5, 6, 7));
            u16x2 g2 = __builtin_elementwise_min(
                __builtin_shufflevector(g4, g4, 0, 1),
                __builtin_shufflevector(g4, g4, 2, 3));
            unsigned int gmin = umin_((unsigned int)g2[0], (unsigned int)g2[1]);
            if ((gmin << 13) < m) {
                int cb = cb0 + i * 8;
                #pragma unroll
                for (int e = 0; e < 8; ++e)
                    ins8(s0, s1, s2, s3, s4, s5, s6, s7, m,
                         ((unsigned int)ch[e] << 13) | (unsigned int)(cb + e));
            }
        }
        size_t kb = (size_t)(colbase + sr) * 1024 + (size_t)bi * 16 + seg * 8;
        uint4 o0; o0.x = s0; o0.y = s1; o0.z = s2; o0.w = s3;
        uint4 o1; o1.x = s4; o1.y = s5; o1.z = s6; o1.w = s7;
        *(uint4*)&keys[kb] = o0;
        *(uint4*)&keys[kb + 4] = o1;
    }
}

// ---------------- fused: merge keys -> sorted top-32, eps-certified selective exact
// rescore -> top-k set, bf16 gather-mean ----------------
__global__ void __launch_bounds__(256) topk_rescore_agg_kernel(
    const unsigned int* __restrict__ keys, const float* __restrict__ x,
    const float* __restrict__ sq, const int* __restrict__ kk,
    const unsigned short* __restrict__ hb, unsigned short* __restrict__ aggb)
{
    const int w = threadIdx.x >> 6;
    const int row = blockIdx.x * 4 + w;
    const int lane = threadIdx.x & 63;
    __shared__ int sidx[4][16];

    // -- phase 1: merge 64x16 per-tile keys -> wave top-32, sorted (seeded) --
    const uint4* kp = (const uint4*)(keys + (size_t)row * 1024 + lane * 16);
    uint4 v0 = kp[0], v1 = kp[1];
    unsigned int s0 = v0.x, s1 = v0.y, s2 = v0.z, s3 = v0.w;
    unsigned int s4 = v1.x, s5 = v1.y, s6 = v1.z, s7 = v1.w;
    unsigned int m = max8_(s0, s1, s2, s3, s4, s5, s6, s7);
    #pragma unroll
    for (int q = 2; q < 4; ++q) {
        uint4 v = kp[q];
        unsigned int gmin = umin_(umin_(v.x, v.y), umin_(v.z, v.w));
        if (gmin < m) {
            ins8(s0, s1, s2, s3, s4, s5, s6, s7, m, v.x);
            ins8(s0, s1, s2, s3, s4, s5, s6, s7, m, v.y);
            ins8(s0, s1, s2, s3, s4, s5, s6, s7, m, v.z);
            ins8(s0, s1, s2, s3, s4, s5, s6, s7, m, v.w);
        }
    }
    unsigned int lmin = umin_(umin_(umin_(s0, s1), umin_(s2, s3)),
                              umin_(umin_(s4, s5), umin_(s6, s7)));
    unsigned int myout = 0;
    for (int t = 0; t < 32; ++t) {
        unsigned int wv = lmin;
        #pragma unroll
        for (int off = 32; off > 0; off >>= 1)
            wv = umin_(wv, (unsigned int)__shfl_xor((int)wv, off));
        if (lane == t) myout = wv;
        if (lmin == wv) {
            s0 = (s0 == wv) ? 0xFFFFFFFFu : s0;
            s1 = (s1 == wv) ? 0xFFFFFFFFu : s1;
            s2 = (s2 == wv) ? 0xFFFFFFFFu : s2;
            s3 = (s3 == wv) ? 0xFFFFFFFFu : s3;
            s4 = (s4 == wv) ? 0xFFFFFFFFu : s4;
            s5 = (s5 == wv) ? 0xFFFFFFFFu : s5;
            s6 = (s6 == wv) ? 0xFFFFFFFFu : s6;
            s7 = (s7 == wv) ? 0xFFFFFFFFu : s7;
            lmin = umin_(umin_(umin_(s0, s1), umin_(s2, s3)),
                         umin_(umin_(s4, s5), umin_(s6, s7)));
        }
    }
    // lane t < 32 holds the t-th smallest key (screened order)
    int myj = (int)(myout & 8191u);
    float dscr = (lane < 32) ? unmap16(myout >> 13) : INFINITY;

    // -- phase 2: eps-certified selective exact rescore --
    const float EPS2 = 2.5f;                 // 2 * (bf16-Gram 6sigma + fp16 round)
    const int k = kk[row];
    float d_k   = __shfl(dscr, k);           // (k+1)-th smallest screened
    float d_km1 = __shfl(dscr, k - 1);       // k-th smallest screened
    bool cin = false, amb = false;
    if (lane < 32) {
        if (lane < k) { cin = (dscr + EPS2 <= d_k); amb = !cin; }
        else          { amb = (dscr < d_km1 + EPS2); }
    }
    unsigned long long cinmask = __ballot(cin);
    unsigned long long ambmask = __ballot(amb);
    int n_in = __popcll(cinmask);
    int msel = k - n_in;                     // how many ambiguous to select

    float d_ex = 0.f;
    if (msel > 0) {
        float xr[6];
        #pragma unroll
        for (int q = 0; q < 6; ++q) xr[q] = x[(size_t)row * DDIM + lane + 64 * q];
        float sqrow = sq[row];
        unsigned long long mm = ambmask;
        while (mm) {
            int c = (int)(__ffsll(mm) - 1);
            mm &= mm - 1;
            int j = __shfl(myj, c);
            const float* xc = x + (size_t)j * DDIM;
            float p = 0.f;
            #pragma unroll
            for (int q = 0; q < 6; ++q) p = fmaf(xr[q], xc[lane + 64 * q], p);
            #pragma unroll
            for (int off = 32; off > 0; off >>= 1) p += __shfl_xor(p, off);
            float d = sqrow + sq[j] - 2.f * p;
            if (lane == c) d_ex = d;
        }
        // rank ambiguous by exact (d, j); select msel smallest
        int selrank = 0;
        unsigned long long mm2 = ambmask;
        while (mm2) {
            int u = (int)(__ffsll(mm2) - 1);
            mm2 &= mm2 - 1;
            float du = __shfl(d_ex, u);
            int ju = __shfl(myj, u);
            if (u != lane && dj_better(du, ju, d_ex, myj)) ++selrank;
        }
        if (amb && selrank < msel)
            sidx[w][n_in + selrank] = myj;
    }
    if (cin) {
        int pos = __popcll(cinmask & ((1ull << lane) - 1ull));
        sidx[w][pos] = myj;
    }
    __syncthreads();

    // -- phase 3: gather-mean of first k neighbors' bf16 h rows --
    float a0 = 0.f, a1 = 0.f, a2 = 0.f, a3 = 0.f;
    for (int t = 0; t < k; ++t) {
        uint2 v = *(const uint2*)(hb + (size_t)sidx[w][t] * HDIM + lane * 4);
        a0 += __uint_as_float(v.x << 16);
        a1 += __uint_as_float(v.x & 0xFFFF0000u);
        a2 += __uint_as_float(v.y << 16);
        a3 += __uint_as_float(v.y & 0xFFFF0000u);
    }
    float inv = 1.f / (float)k;
    unsigned int b0 = rne_bf16(a0 * inv);
    unsigned int b1 = rne_bf16(a1 * inv);
    unsigned int b2 = rne_bf16(a2 * inv);
    unsigned int b3 = rne_bf16(a3 * inv);
    uint2 o; o.x = b0 | (b1 << 16); o.y = b2 | (b3 << 16);
    *(uint2*)(aggb + (size_t)row * HDIM + lane * 4) = o;
}

// ---------------- LayerNorm(h + r) * g + b, then @ W_fc + b_fc (one row per wave) ----------------
__global__ void __launch_bounds__(256) ln_fc_kernel(
    const float* __restrict__ h, const float* __restrict__ r,
    const float* __restrict__ g, const float* __restrict__ bb,
    const float* __restrict__ W_fc, const float* __restrict__ b_fc,
    float* __restrict__ out)
{
    const int row = blockIdx.x * 4 + (threadIdx.x >> 6);
    const int lane = threadIdx.x & 63;
    const float* hp = h + (size_t)row * HDIM;
    const float* rp = r + (size_t)row * HDIM;

    float z[4];
    #pragma unroll
    for (int q = 0; q < 4; ++q)
        z[q] = hp[lane + 64 * q] + rp[lane + 64 * q];

    float s = z[0] + z[1] + z[2] + z[3];
    float s2 = z[0]*z[0] + z[1]*z[1] + z[2]*z[2] + z[3]*z[3];
    #pragma unroll
    for (int off = 32; off > 0; off >>= 1) {
        s += __shfl_xor(s, off);
        s2 += __shfl_xor(s2, off);
    }
    float mu = s / 256.f;
    float rstd = rsqrtf(s2 / 256.f - mu * mu + LN_EPS);

    float p[6] = {0.f, 0.f, 0.f, 0.f, 0.f, 0.f};
    #pragma unroll
    for (int q = 0; q < 4; ++q) {
        int i = lane + 64 * q;
        float val = (z[q] - mu) * rstd * g[i] + bb[i];
        #pragma unroll
        for (int c = 0; c < 6; ++c)
            p[c] = fmaf(val, W_fc[i * 6 + c], p[c]);
    }
    #pragma unroll
    for (int c = 0; c < 6; ++c)
        #pragma unroll
        for (int off = 32; off > 0; off >>= 1) p[c] += __shfl_xor(p[c], off);

    if (lane < 6) {
        float o = p[0];
        o = (lane == 1) ? p[1] : o;
        o = (lane == 2) ? p[2] : o;
        o = (lane == 3) ? p[3] : o;
        o = (lane == 4) ? p[4] : o;
        o = (lane == 5) ? p[5] : o;
        out[(size_t)row * CDIM + lane] = o + b_fc[lane];
    }
}

extern "C" void kernel_launch(void* const* d_in, const int* in_sizes, int n_in,
                              void* d_out, int out_size, void* d_ws, size_t ws_size,
                              hipStream_t stream) {
    const float* x      = (const float*)d_in[0];
    const float* W_proj = (const float*)d_in[1];
    const float* b_proj = (const float*)d_in[2];
    const float* W_tau  = (const float*)d_in[3];
    const float* b_tau  = (const float*)d_in[4];
    const float* W_res  = (const float*)d_in[5];
    const float* b_res  = (const float*)d_in[6];
    const float* ln_g   = (const float*)d_in[7];
    const float* ln_b   = (const float*)d_in[8];
    const float* W_fc   = (const float*)d_in[9];
    const float* b_fc   = (const float*)d_in[10];
    float* out = (float*)d_out;

    char* ws = (char*)d_ws;
    float* sq   = (float*)ws;                        ws += (size_t)NROWS * 4;
    int*   kk   = (int*)ws;                          ws += (size_t)NROWS * 4;
    float* h    = (float*)ws;                        ws += (size_t)NROWS * HDIM * 4;
    float* r    = (float*)ws;                        ws += (size_t)NROWS * HDIM * 4;
    unsigned short* xb   = (unsigned short*)ws;      ws += (size_t)NROWS * DDIM * 2;
    unsigned short* hbuf = (unsigned short*)ws;      ws += (size_t)NROWS * HDIM * 2;
    unsigned short* aggb = (unsigned short*)ws;      ws += (size_t)NROWS * HDIM * 2;
    unsigned short* wpT  = (unsigned short*)ws;      ws += (size_t)DDIM * HDIM * 2;
    unsigned short* wrT  = (unsigned short*)ws;      ws += (size_t)HDIM * HDIM * 2;
    ws = (char*)(((size_t)ws + 255) & ~(size_t)255);
    unsigned int* keys = (unsigned int*)ws;          ws += (size_t)NROWS * 1024 * 4;   // 32 MB

    const int prepW = (DDIM * HDIM + HDIM * HDIM + 255) / 256;
    prep_kernel<<<NROWS / 4 + prepW, 256, 0, stream>>>(
        x, W_tau, b_tau, xb, sq, kk, W_proj, wpT, W_res, wrT);
    mfma_gemm_bias_relu_kernel<<<dim3(NROWS / 128, HDIM / 128), 256, 0, stream>>>(
        xb, wpT, b_proj, h, hbuf, DDIM);
    dist_topk_kernel<<<(NROWS/128) * (NROWS/128 + 1) / 2, 256, 0, stream>>>(xb, sq, keys);
    topk_rescore_agg_kernel<<<NROWS / 4, 256, 0, stream>>>(keys, x, sq, kk, hbuf, aggb);
    mfma_gemm_bias_relu_kernel<<<dim3(NROWS / 128, HDIM / 128), 256, 0, stream>>>(
        aggb, wrT, b_res, r, (unsigned short*)nullptr, HDIM);
    ln_fc_kernel<<<NROWS / 4, 256, 0, stream>>>(h, r, ln_g, ln_b, W_fc, b_fc, out);
}